// Round 1
// baseline (499.762 us; speedup 1.0000x reference)
//
#include <hip/hip_runtime.h>
#include <cstdint>
#include <cstddef>

namespace {

constexpr int kS  = 2048;   // sequence
constexpr int kD  = 1024;   // model dim
constexpr int kHD = 64;     // head dim
constexpr int kTOK = 4096;  // B * S rows

typedef float f32x4 __attribute__((ext_vector_type(4)));
typedef __bf16 bf16x8 __attribute__((ext_vector_type(8)));
typedef unsigned short u16x8 __attribute__((ext_vector_type(8)));

__device__ __forceinline__ unsigned short f2b(float f){
  unsigned int u = __builtin_bit_cast(unsigned int, f);
  u += 0x7fffu + ((u >> 16) & 1u);      // RNE
  return (unsigned short)(u >> 16);
}

__device__ __forceinline__ bf16x8 ldfrag(const unsigned short* p){
  return __builtin_bit_cast(bf16x8, *(const u16x8*)p);
}

__device__ __forceinline__ void gl_lds16(const void* g, void* l){
  // async global->LDS, 16B per lane; LDS dest is wave-uniform base + lane*16
  __builtin_amdgcn_global_load_lds(
      (__attribute__((address_space(1))) void*)(void*)g,
      (__attribute__((address_space(3))) void*)l, 16, 0, 0);
}

// ---------------- f32 -> bf16 elementwise ----------------
__global__ __launch_bounds__(256) void cvt_bf16_kern(const float* __restrict__ X,
                                                     unsigned short* __restrict__ Y){
  int i = blockIdx.x * 256 + threadIdx.x;
  float4 v = ((const float4*)X)[i];
  ((ushort4*)Y)[i] = make_ushort4(f2b(v.x), f2b(v.y), f2b(v.z), f2b(v.w));
}

// ---------------- W[K,N] f32 -> Wt[N,K] bf16 (transpose+convert) ----------------
__global__ __launch_bounds__(256) void wtrans_kern(const float* __restrict__ W,
                                                   unsigned short* __restrict__ Wt,
                                                   int K, int N){
  __shared__ float t[32][33];
  int n0 = blockIdx.x * 32, k0 = blockIdx.y * 32;
  int tx = threadIdx.x & 31, ty = threadIdx.x >> 5;   // ty in [0,8)
  #pragma unroll
  for (int i = 0; i < 32; i += 8)
    t[ty + i][tx] = W[(size_t)(k0 + ty + i) * N + n0 + tx];
  __syncthreads();
  #pragma unroll
  for (int i = 0; i < 32; i += 8)
    Wt[(size_t)(n0 + ty + i) * K + k0 + tx] = f2b(t[tx][ty + i]);
}

// ---------------- per-head V transpose: [bh][S][64] -> [bh][64][S] (bf16) ----------------
__global__ __launch_bounds__(256) void vtrans_kern(const unsigned short* __restrict__ V,
                                                   unsigned short* __restrict__ Vt){
  __shared__ unsigned short t[64][65];
  int bh = blockIdx.y, s0 = blockIdx.x * 64;
  const unsigned short* Vh = V + (size_t)bh * kS * kHD;
  unsigned short* Vth = Vt + (size_t)bh * kHD * kS;
  int tx = threadIdx.x & 63, ty = threadIdx.x >> 6;   // ty in [0,4)
  #pragma unroll
  for (int i = 0; i < 64; i += 4)
    t[ty + i][tx] = Vh[(size_t)(s0 + ty + i) * kHD + tx];
  __syncthreads();
  #pragma unroll
  for (int i = 0; i < 64; i += 4)
    Vth[(size_t)(ty + i) * kS + s0 + tx] = t[tx][ty + i];
}

// ---------------- GEMM: C[M,N] = A[M,K]*Bt[N,K]^T + bias (bf16 in, f32 acc) ----------------
// m97 structure: 128x128 tile, BK=32, 4 waves (2x2), global_load_lds staging.
template <int OUT_BF16, int ACT_GELU>
__global__ __launch_bounds__(256) void gemm_bt_kern(const unsigned short* __restrict__ A,
                                                    const unsigned short* __restrict__ Bt,
                                                    const float* __restrict__ bias,
                                                    void* __restrict__ C,
                                                    int M, int N, int K){
  __shared__ unsigned short As[128 * 32];
  __shared__ unsigned short Bs[128 * 32];
  const int tid  = threadIdx.x;
  const int wave = tid >> 6, lane = tid & 63;
  const int wr = wave >> 1, wc = wave & 1;
  const int m0 = blockIdx.y << 7, n0 = blockIdx.x << 7;
  const int lr = lane & 15, lk = lane >> 4;
  const int ch0 = wave * 2, ch1 = wave * 2 + 1;
  const int sr0 = ch0 * 16 + (lane >> 2), sr1 = ch1 * 16 + (lane >> 2);
  const int sc  = (lane & 3) * 8;
  f32x4 acc[4][4] = {};
  for (int k0 = 0; k0 < K; k0 += 32){
    __syncthreads();
    gl_lds16(A  + (size_t)(m0 + sr0) * K + k0 + sc, As + ch0 * 512);
    gl_lds16(A  + (size_t)(m0 + sr1) * K + k0 + sc, As + ch1 * 512);
    gl_lds16(Bt + (size_t)(n0 + sr0) * K + k0 + sc, Bs + ch0 * 512);
    gl_lds16(Bt + (size_t)(n0 + sr1) * K + k0 + sc, Bs + ch1 * 512);
    __syncthreads();
    bf16x8 af[4], bfr[4];
    #pragma unroll
    for (int m = 0; m < 4; ++m)
      af[m] = ldfrag(&As[(wr * 64 + m * 16 + lr) * 32 + lk * 8]);
    #pragma unroll
    for (int n = 0; n < 4; ++n)
      bfr[n] = ldfrag(&Bs[(wc * 64 + n * 16 + lr) * 32 + lk * 8]);
    #pragma unroll
    for (int m = 0; m < 4; ++m)
      #pragma unroll
      for (int n = 0; n < 4; ++n)
        acc[m][n] = __builtin_amdgcn_mfma_f32_16x16x32_bf16(af[m], bfr[n], acc[m][n], 0, 0, 0);
  }
  #pragma unroll
  for (int n = 0; n < 4; ++n){
    const int col = n0 + wc * 64 + n * 16 + lr;
    const float bv = bias[col];
    #pragma unroll
    for (int m = 0; m < 4; ++m){
      #pragma unroll
      for (int j = 0; j < 4; ++j){
        const int row = m0 + wr * 64 + m * 16 + lk * 4 + j;
        float v = acc[m][n][j] + bv;
        if (ACT_GELU) v = 0.5f * v * (1.0f + erff(v * 0.70710678118654752f));
        if (OUT_BF16) ((unsigned short*)C)[(size_t)row * N + col] = f2b(v);
        else          ((float*)C)[(size_t)row * N + col] = v;
      }
    }
  }
}

// ---------------- flash attention: per (b,h), Q/K [2048,64], Vt [64,2048] ----------------
__global__ __launch_bounds__(256) void attn_kern(const unsigned short* __restrict__ Q,
                                                 const unsigned short* __restrict__ Kb,
                                                 const unsigned short* __restrict__ Vt,
                                                 const int* __restrict__ mask,
                                                 unsigned short* __restrict__ O){
  __shared__ unsigned short Ks[64 * 64];
  __shared__ unsigned short Vs[64 * 64];        // [d][t] for this tile
  __shared__ unsigned short Ps[4][32 * 64];     // per-wave P
  const int tid = threadIdx.x;
  const int wave = tid >> 6, lane = tid & 63;
  const int lr = lane & 15, lk = lane >> 4;
  const int bh = blockIdx.y;
  const size_t hoff = (size_t)bh * kS * kHD;
  const unsigned short* Qh = Q  + hoff;
  const unsigned short* Kh = Kb + hoff;
  const unsigned short* Vh = Vt + hoff;         // [64][S]
  const int qrow = blockIdx.x * 128 + wave * 32;
  bf16x8 qf[2][2];
  #pragma unroll
  for (int m = 0; m < 2; ++m)
    #pragma unroll
    for (int kk = 0; kk < 2; ++kk)
      qf[m][kk] = ldfrag(Qh + (size_t)(qrow + m * 16 + lr) * 64 + kk * 32 + lk * 8);
  f32x4 accO[2][4] = {};
  float mrow[2][4], lrow[2][4];
  #pragma unroll
  for (int m = 0; m < 2; ++m)
    #pragma unroll
    for (int j = 0; j < 4; ++j){ mrow[m][j] = -__builtin_inff(); lrow[m][j] = 0.f; }
  const int ch0 = wave * 2, ch1 = ch0 + 1;
  const int krA = (lane >> 3), kc = (lane & 7) * 8;
  unsigned short* Pw = &Ps[wave][0];
  for (int t0 = 0; t0 < kS; t0 += 64){
    __syncthreads();
    gl_lds16(Kh + (size_t)(t0 + ch0 * 8 + krA) * 64 + kc, Ks + ch0 * 512);
    gl_lds16(Kh + (size_t)(t0 + ch1 * 8 + krA) * 64 + kc, Ks + ch1 * 512);
    gl_lds16(Vh + (size_t)(ch0 * 8 + krA) * kS + t0 + kc, Vs + ch0 * 512);
    gl_lds16(Vh + (size_t)(ch1 * 8 + krA) * kS + t0 + kc, Vs + ch1 * 512);
    __syncthreads();
    f32x4 sa[2][4] = {};
    #pragma unroll
    for (int kk = 0; kk < 2; ++kk){
      bf16x8 kf[4];
      #pragma unroll
      for (int n = 0; n < 4; ++n)
        kf[n] = ldfrag(&Ks[(n * 16 + lr) * 64 + kk * 32 + lk * 8]);
      #pragma unroll
      for (int m = 0; m < 2; ++m)
        #pragma unroll
        for (int n = 0; n < 4; ++n)
          sa[m][n] = __builtin_amdgcn_mfma_f32_16x16x32_bf16(qf[m][kk], kf[n], sa[m][n], 0, 0, 0);
    }
    #pragma unroll
    for (int m = 0; m < 2; ++m){
      #pragma unroll
      for (int j = 0; j < 4; ++j){
        const int srow = qrow + m * 16 + lk * 4 + j;
        const int* mp = mask + (size_t)srow * kS + t0;
        float sv[4];
        float rmax = -__builtin_inff();
        #pragma unroll
        for (int n = 0; n < 4; ++n){
          float v = sa[m][n][j] * 0.125f;          // 1/sqrt(64)
          if (mp[n * 16 + lr] == 0) v = -9e15f;
          sv[n] = v;
          rmax = fmaxf(rmax, v);
        }
        #pragma unroll
        for (int d = 1; d < 16; d <<= 1) rmax = fmaxf(rmax, __shfl_xor(rmax, d));
        const float mn  = fmaxf(mrow[m][j], rmax);
        const float esc = __expf(mrow[m][j] - mn);
        float ps = 0.f;
        #pragma unroll
        for (int n = 0; n < 4; ++n){
          float p = __expf(sv[n] - mn);
          ps += p;
          Pw[(m * 16 + lk * 4 + j) * 64 + n * 16 + lr] = f2b(p);
        }
        #pragma unroll
        for (int d = 1; d < 16; d <<= 1) ps += __shfl_xor(ps, d);
        lrow[m][j] = lrow[m][j] * esc + ps;
        mrow[m][j] = mn;
        #pragma unroll
        for (int dd = 0; dd < 4; ++dd) accO[m][dd][j] *= esc;
      }
    }
    __syncthreads();   // P visible (and uniform with staging barrier pattern)
    #pragma unroll
    for (int kk = 0; kk < 2; ++kk){
      bf16x8 pf[2], vf[4];
      #pragma unroll
      for (int m = 0; m < 2; ++m)
        pf[m] = ldfrag(&Pw[(m * 16 + lr) * 64 + kk * 32 + lk * 8]);
      #pragma unroll
      for (int dd = 0; dd < 4; ++dd)
        vf[dd] = ldfrag(&Vs[(dd * 16 + lr) * 64 + kk * 32 + lk * 8]);
      #pragma unroll
      for (int m = 0; m < 2; ++m)
        #pragma unroll
        for (int dd = 0; dd < 4; ++dd)
          accO[m][dd] = __builtin_amdgcn_mfma_f32_16x16x32_bf16(pf[m], vf[dd], accO[m][dd], 0, 0, 0);
    }
  }
  #pragma unroll
  for (int m = 0; m < 2; ++m){
    #pragma unroll
    for (int j = 0; j < 4; ++j){
      const float inv = 1.0f / lrow[m][j];
      const int row = qrow + m * 16 + lk * 4 + j;
      #pragma unroll
      for (int dd = 0; dd < 4; ++dd)
        O[hoff + (size_t)row * 64 + dd * 16 + lr] = f2b(accO[m][dd][j] * inv);
    }
  }
}

// ---------------- fused add + LayerNorm (writes f32 residual + optional bf16) ----------------
__global__ __launch_bounds__(256) void add_ln_kern(const float* __restrict__ X,
                                                   const float* __restrict__ R,
                                                   const float* __restrict__ g,
                                                   const float* __restrict__ be,
                                                   float* __restrict__ Yf,
                                                   unsigned short* __restrict__ Yb){
  const int row = blockIdx.x;
  const int tid = threadIdx.x;
  const float4 xv = ((const float4*)(X + (size_t)row * kD))[tid];
  const float4 rv = ((const float4*)(R + (size_t)row * kD))[tid];
  const float a0 = xv.x + rv.x, a1 = xv.y + rv.y, a2 = xv.z + rv.z, a3 = xv.w + rv.w;
  float s = a0 + a1 + a2 + a3;
  float q = a0*a0 + a1*a1 + a2*a2 + a3*a3;
  #pragma unroll
  for (int d = 1; d < 64; d <<= 1){ s += __shfl_xor(s, d); q += __shfl_xor(q, d); }
  __shared__ float red[8];
  const int wave = tid >> 6, lane = tid & 63;
  if (lane == 0){ red[wave] = s; red[4 + wave] = q; }
  __syncthreads();
  s = red[0] + red[1] + red[2] + red[3];
  q = red[4] + red[5] + red[6] + red[7];
  const float mu   = s * (1.0f / kD);
  const float var  = q * (1.0f / kD) - mu * mu;
  const float rstd = rsqrtf(var + 1e-5f);
  const float4 gv = ((const float4*)g)[tid];
  const float4 bv = ((const float4*)be)[tid];
  const float y0 = (a0 - mu) * rstd * gv.x + bv.x;
  const float y1 = (a1 - mu) * rstd * gv.y + bv.y;
  const float y2 = (a2 - mu) * rstd * gv.z + bv.z;
  const float y3 = (a3 - mu) * rstd * gv.w + bv.w;
  ((float4*)(Yf + (size_t)row * kD))[tid] = make_float4(y0, y1, y2, y3);
  if (Yb)
    ((ushort4*)(Yb + (size_t)row * kD))[tid] = make_ushort4(f2b(y0), f2b(y1), f2b(y2), f2b(y3));
}

} // namespace

extern "C" void kernel_launch(void* const* d_in, const int* in_sizes, int n_in,
                              void* d_out, int out_size, void* d_ws, size_t ws_size,
                              hipStream_t stream){
  (void)in_sizes; (void)n_in; (void)out_size;
  const float* x   = (const float*)d_in[0];
  const int*   mask= (const int*)d_in[1];
  const float* Wq  = (const float*)d_in[2];  const float* bq  = (const float*)d_in[3];
  const float* Wk  = (const float*)d_in[4];  const float* bk  = (const float*)d_in[5];
  const float* Wv  = (const float*)d_in[6];  const float* bv  = (const float*)d_in[7];
  const float* Wo  = (const float*)d_in[8];  const float* bo  = (const float*)d_in[9];
  const float* W1  = (const float*)d_in[10]; const float* b1  = (const float*)d_in[11];
  const float* W2  = (const float*)d_in[12]; const float* b2  = (const float*)d_in[13];
  const float* g1  = (const float*)d_in[14]; const float* be1 = (const float*)d_in[15];
  const float* g2  = (const float*)d_in[16]; const float* be2 = (const float*)d_in[17];

  char* ws = (char*)d_ws;
  const size_t MB = 1024 * 1024;
  if (ws_size < 96 * MB) return;   // need 96 MB of scratch

  unsigned short* WqT = (unsigned short*)(ws + 0 * MB);   // 2 MB each
  unsigned short* WkT = (unsigned short*)(ws + 2 * MB);
  unsigned short* WvT = (unsigned short*)(ws + 4 * MB);
  unsigned short* WoT = (unsigned short*)(ws + 6 * MB);
  unsigned short* W1T = (unsigned short*)(ws + 8 * MB);   // 8 MB
  unsigned short* W2T = (unsigned short*)(ws + 16 * MB);  // 8 MB
  unsigned short* xb  = (unsigned short*)(ws + 24 * MB);  // 8 MB
  unsigned short* qb  = (unsigned short*)(ws + 32 * MB);  // 8 MB
  unsigned short* kb  = (unsigned short*)(ws + 40 * MB);  // 8 MB
  unsigned short* vb  = (unsigned short*)(ws + 48 * MB);  // 8 MB
  unsigned short* vt  = (unsigned short*)(ws + 56 * MB);  // 8 MB
  unsigned short* av  = (unsigned short*)(ws + 64 * MB);  // 8 MB
  // aliased regions (lifetimes verified):
  float* attn         = (float*)(ws + 24 * MB);           // 16 MB over xb+qb (dead)
  float* y32          = (float*)(ws + 40 * MB);           // 16 MB over kb+vb (dead)
  unsigned short* yb  = (unsigned short*)(ws + 56 * MB);  //  8 MB over vt   (dead)
  unsigned short* hb  = (unsigned short*)(ws + 64 * MB);  // 32 MB over av   (dead)
  float* ffo          = (float*)(ws + 24 * MB);           // 16 MB over attn (dead)

  dim3 blk(256);
  wtrans_kern<<<dim3(32, 32),  blk, 0, stream>>>(Wq, WqT, 1024, 1024);
  wtrans_kern<<<dim3(32, 32),  blk, 0, stream>>>(Wk, WkT, 1024, 1024);
  wtrans_kern<<<dim3(32, 32),  blk, 0, stream>>>(Wv, WvT, 1024, 1024);
  wtrans_kern<<<dim3(32, 32),  blk, 0, stream>>>(Wo, WoT, 1024, 1024);
  wtrans_kern<<<dim3(128, 32), blk, 0, stream>>>(W1, W1T, 1024, 4096);
  wtrans_kern<<<dim3(32, 128), blk, 0, stream>>>(W2, W2T, 4096, 1024);
  cvt_bf16_kern<<<dim3(kTOK * kD / 1024), blk, 0, stream>>>(x, xb);

  gemm_bt_kern<1,0><<<dim3(8, 32), blk, 0, stream>>>(xb, WqT, bq, qb, 4096, 1024, 1024);
  gemm_bt_kern<1,0><<<dim3(8, 32), blk, 0, stream>>>(xb, WkT, bk, kb, 4096, 1024, 1024);
  gemm_bt_kern<1,0><<<dim3(8, 32), blk, 0, stream>>>(xb, WvT, bv, vb, 4096, 1024, 1024);

  vtrans_kern<<<dim3(32, 32), blk, 0, stream>>>(vb, vt);
  attn_kern<<<dim3(16, 32), blk, 0, stream>>>(qb, kb, vt, mask, av);

  gemm_bt_kern<0,0><<<dim3(8, 32), blk, 0, stream>>>(av, WoT, bo, attn, 4096, 1024, 1024);
  add_ln_kern<<<dim3(4096), blk, 0, stream>>>(x, attn, g1, be1, y32, yb);

  gemm_bt_kern<1,1><<<dim3(32, 32), blk, 0, stream>>>(yb, W1T, b1, hb, 4096, 4096, 1024);
  gemm_bt_kern<0,0><<<dim3(8, 32), blk, 0, stream>>>(hb, W2T, b2, ffo, 4096, 1024, 4096);
  add_ln_kern<<<dim3(4096), blk, 0, stream>>>(y32, ffo, g2, be2, (float*)d_out, nullptr);
}

// Round 2
// 419.736 us; speedup vs baseline: 1.1907x; 1.1907x over previous
//
#include <hip/hip_runtime.h>
#include <cstdint>
#include <cstddef>

namespace {

constexpr int kS  = 2048;   // sequence
constexpr int kD  = 1024;   // model dim
constexpr int kHD = 64;     // head dim
constexpr int kTOK = 4096;  // B * S rows

typedef float f32x4 __attribute__((ext_vector_type(4)));
typedef __bf16 bf16x8 __attribute__((ext_vector_type(8)));
typedef unsigned short u16x8 __attribute__((ext_vector_type(8)));

__device__ __forceinline__ unsigned short f2b(float f){
  unsigned int u = __builtin_bit_cast(unsigned int, f);
  u += 0x7fffu + ((u >> 16) & 1u);      // RNE
  return (unsigned short)(u >> 16);
}

__device__ __forceinline__ bf16x8 ldfrag(const unsigned short* p){
  return __builtin_bit_cast(bf16x8, *(const u16x8*)p);
}

__device__ __forceinline__ float fexp2(float x){
#if __has_builtin(__builtin_amdgcn_exp2f)
  return __builtin_amdgcn_exp2f(x);
#else
  return exp2f(x);
#endif
}

__device__ __forceinline__ void gl_lds16(const void* g, void* l){
  // async global->LDS, 16B per lane; LDS dest is wave-uniform base + lane*16
  __builtin_amdgcn_global_load_lds(
      (__attribute__((address_space(1))) void*)(void*)g,
      (__attribute__((address_space(3))) void*)l, 16, 0, 0);
}

// Stage a 64x64 bf16 tile (row-major in LDS, 128B rows) with T2 slot-swizzle:
// LDS stays linear (gl_lds requirement); the global SOURCE column is
// pre-swizzled so that LDS slot s of row r holds global slot s^(r&7).
__device__ __forceinline__ void stage64x64(const unsigned short* gbase, size_t gstride,
                                           unsigned short* ldsbase, int wave, int lane){
  #pragma unroll
  for (int i = 0; i < 2; ++i){
    const int lin = i*4096 + wave*1024 + lane*16;   // byte offset in tile
    const int r = lin >> 7;                          // row (128B rows)
    const int s = (lin >> 4) & 7;                    // 16B slot within row
    gl_lds16(gbase + (size_t)r * gstride + (((s ^ r) & 7) << 3),
             (char*)ldsbase + i*4096 + wave*1024);
  }
}

// swizzled 16B fragment read: slot in [0,8)
__device__ __forceinline__ bf16x8 ld_swz(const unsigned short* tile, int row, int slot){
  return ldfrag(tile + row*64 + (((slot ^ row) & 7) << 3));
}

// ---------------- f32 -> bf16 elementwise ----------------
__global__ __launch_bounds__(256) void cvt_bf16_kern(const float* __restrict__ X,
                                                     unsigned short* __restrict__ Y){
  int i = blockIdx.x * 256 + threadIdx.x;
  float4 v = ((const float4*)X)[i];
  ((ushort4*)Y)[i] = make_ushort4(f2b(v.x), f2b(v.y), f2b(v.z), f2b(v.w));
}

// ---------------- mask int32 [S][S] -> bit-packed u64 [S][S/64] ----------------
__global__ __launch_bounds__(256) void maskbits_kern(const int* __restrict__ mask,
                                                     unsigned long long* __restrict__ mb){
  const int gw   = (blockIdx.x * 256 + threadIdx.x) >> 6;   // global wave id
  const int lane = threadIdx.x & 63;
  const int row  = gw >> 5, word = gw & 31;
  const int m = mask[(size_t)row * kS + word * 64 + lane];
  const unsigned long long b = __ballot(m != 0);
  if (lane == 0) mb[(size_t)row * 32 + word] = b;
}

// ---------------- W[K,N] f32 -> Wt[N,K] bf16 (transpose+convert) ----------------
__global__ __launch_bounds__(256) void wtrans_kern(const float* __restrict__ W,
                                                   unsigned short* __restrict__ Wt,
                                                   int K, int N){
  __shared__ float t[32][33];
  int n0 = blockIdx.x * 32, k0 = blockIdx.y * 32;
  int tx = threadIdx.x & 31, ty = threadIdx.x >> 5;   // ty in [0,8)
  #pragma unroll
  for (int i = 0; i < 32; i += 8)
    t[ty + i][tx] = W[(size_t)(k0 + ty + i) * N + n0 + tx];
  __syncthreads();
  #pragma unroll
  for (int i = 0; i < 32; i += 8)
    Wt[(size_t)(n0 + ty + i) * K + k0 + tx] = f2b(t[tx][ty + i]);
}

// ---------------- per-head V transpose: [bh][S][64] -> [bh][64][S] (bf16) ----------------
__global__ __launch_bounds__(256) void vtrans_kern(const unsigned short* __restrict__ V,
                                                   unsigned short* __restrict__ Vt){
  __shared__ unsigned short t[64][65];
  int bh = blockIdx.y, s0 = blockIdx.x * 64;
  const unsigned short* Vh = V + (size_t)bh * kS * kHD;
  unsigned short* Vth = Vt + (size_t)bh * kHD * kS;
  int tx = threadIdx.x & 63, ty = threadIdx.x >> 6;   // ty in [0,4)
  #pragma unroll
  for (int i = 0; i < 64; i += 4)
    t[ty + i][tx] = Vh[(size_t)(s0 + ty + i) * kHD + tx];
  __syncthreads();
  #pragma unroll
  for (int i = 0; i < 64; i += 4)
    Vth[(size_t)(ty + i) * kS + s0 + tx] = t[tx][ty + i];
}

// ---------------- GEMM: C[M,N] = A[M,K]*Bt[N,K]^T + bias (bf16 in, f32 acc) ----------------
template <int OUT_BF16, int ACT_GELU>
__global__ __launch_bounds__(256) void gemm_bt_kern(const unsigned short* __restrict__ A,
                                                    const unsigned short* __restrict__ Bt,
                                                    const float* __restrict__ bias,
                                                    void* __restrict__ C,
                                                    int M, int N, int K){
  __shared__ unsigned short As[128 * 32];
  __shared__ unsigned short Bs[128 * 32];
  const int tid  = threadIdx.x;
  const int wave = tid >> 6, lane = tid & 63;
  const int wr = wave >> 1, wc = wave & 1;
  const int m0 = blockIdx.y << 7, n0 = blockIdx.x << 7;
  const int lr = lane & 15, lk = lane >> 4;
  const int ch0 = wave * 2, ch1 = wave * 2 + 1;
  const int sr0 = ch0 * 16 + (lane >> 2), sr1 = ch1 * 16 + (lane >> 2);
  const int sc  = (lane & 3) * 8;
  f32x4 acc[4][4] = {};
  for (int k0 = 0; k0 < K; k0 += 32){
    __syncthreads();
    gl_lds16(A  + (size_t)(m0 + sr0) * K + k0 + sc, As + ch0 * 512);
    gl_lds16(A  + (size_t)(m0 + sr1) * K + k0 + sc, As + ch1 * 512);
    gl_lds16(Bt + (size_t)(n0 + sr0) * K + k0 + sc, Bs + ch0 * 512);
    gl_lds16(Bt + (size_t)(n0 + sr1) * K + k0 + sc, Bs + ch1 * 512);
    __syncthreads();
    bf16x8 af[4], bfr[4];
    #pragma unroll
    for (int m = 0; m < 4; ++m)
      af[m] = ldfrag(&As[(wr * 64 + m * 16 + lr) * 32 + lk * 8]);
    #pragma unroll
    for (int n = 0; n < 4; ++n)
      bfr[n] = ldfrag(&Bs[(wc * 64 + n * 16 + lr) * 32 + lk * 8]);
    #pragma unroll
    for (int m = 0; m < 4; ++m)
      #pragma unroll
      for (int n = 0; n < 4; ++n)
        acc[m][n] = __builtin_amdgcn_mfma_f32_16x16x32_bf16(af[m], bfr[n], acc[m][n], 0, 0, 0);
  }
  #pragma unroll
  for (int n = 0; n < 4; ++n){
    const int col = n0 + wc * 64 + n * 16 + lr;
    const float bv = bias[col];
    #pragma unroll
    for (int m = 0; m < 4; ++m){
      #pragma unroll
      for (int j = 0; j < 4; ++j){
        const int row = m0 + wr * 64 + m * 16 + lk * 4 + j;
        float v = acc[m][n][j] + bv;
        if (ACT_GELU) v = 0.5f * v * (1.0f + erff(v * 0.70710678118654752f));
        if (OUT_BF16) ((unsigned short*)C)[(size_t)row * N + col] = f2b(v);
        else          ((float*)C)[(size_t)row * N + col] = v;
      }
    }
  }
}

// ---------------- flash attention v2: swapped QK^T, in-register softmax ----------------
// 4 waves x 32 q-rows = 128 rows/block; KV tile 64; K/V double-buffered, slot-swizzled.
__global__ __launch_bounds__(256) void attn_kern(const unsigned short* __restrict__ Q,
                                                 const unsigned short* __restrict__ Kb,
                                                 const unsigned short* __restrict__ Vt,
                                                 const unsigned long long* __restrict__ mbits,
                                                 unsigned short* __restrict__ O){
  __shared__ unsigned short Ks[2][64 * 64];
  __shared__ unsigned short Vs[2][64 * 64];     // [d][t], swizzled
  __shared__ unsigned short Ps[4][32 * 64];     // per-wave P [qrow][key], swizzled
  const int tid = threadIdx.x;
  const int wave = tid >> 6, lane = tid & 63;
  const int lr = lane & 15, lk = lane >> 4;
  const int bh = blockIdx.y;
  const size_t hoff = (size_t)bh * kS * kHD;
  const unsigned short* Qh = Q  + hoff;
  const unsigned short* Kh = Kb + hoff;
  const unsigned short* Vh = Vt + hoff;         // [64][S]
  const int qbase = blockIdx.x * 128 + wave * 32;
  constexpr float kScl = 0.18033688011112042f;  // 0.125 * log2(e)  (base-2 softmax)
  constexpr float kNEG = -9e15f;

  // Q as MFMA B-fragments (col = qrow = lr), kept in registers
  bf16x8 qf[2][2];
  #pragma unroll
  for (int q = 0; q < 2; ++q)
    #pragma unroll
    for (int kk = 0; kk < 2; ++kk)
      qf[q][kk] = ldfrag(Qh + (size_t)(qbase + q * 16 + lr) * 64 + kk * 32 + lk * 8);

  f32x4 accO[2][4] = {};
  float m2[2] = { -__builtin_inff(), -__builtin_inff() };
  float lsum[2] = { 0.f, 0.f };
  unsigned short* Pw = Ps[wave];

  const unsigned long long* mrp0 = mbits + (size_t)(qbase + lr) * 32;
  const unsigned long long* mrp1 = mbits + (size_t)(qbase + 16 + lr) * 32;
  unsigned long long mb0 = mrp0[0], mb1 = mrp1[0];

  // prologue: stage tile 0
  stage64x64(Kh, 64, Ks[0], wave, lane);
  stage64x64(Vh, kS, Vs[0], wave, lane);
  __syncthreads();

  int cur = 0;
  for (int t = 0; t < kS / 64; ++t){
    // issue next tile's staging first (overlaps with compute; drained by end barrier)
    unsigned long long mbn0 = 0, mbn1 = 0;
    if (t < kS / 64 - 1){
      stage64x64(Kh + (size_t)(t + 1) * 64 * 64, 64, Ks[cur ^ 1], wave, lane);
      stage64x64(Vh + (size_t)(t + 1) * 64,      kS, Vs[cur ^ 1], wave, lane);
      mbn0 = mrp0[t + 1]; mbn1 = mrp1[t + 1];
    }
    // QK^T swapped: S^T[key, qrow] = mfma(A=K, B=Q); lane holds 16 keys of qrow lr
    f32x4 sa[2][4] = {};
    #pragma unroll
    for (int kk = 0; kk < 2; ++kk){
      bf16x8 kf[4];
      #pragma unroll
      for (int n = 0; n < 4; ++n)
        kf[n] = ld_swz(Ks[cur], n * 16 + lr, kk * 4 + lk);
      #pragma unroll
      for (int q = 0; q < 2; ++q)
        #pragma unroll
        for (int n = 0; n < 4; ++n)
          sa[q][n] = __builtin_amdgcn_mfma_f32_16x16x32_bf16(kf[n], qf[q][kk], sa[q][n], 0, 0, 0);
    }
    // in-register online softmax (one q-row per lane, replicated over lk groups)
    #pragma unroll
    for (int q = 0; q < 2; ++q){
      const unsigned long long mm = (q == 0) ? mb0 : mb1;
      float vmax = -__builtin_inff();
      #pragma unroll
      for (int n = 0; n < 4; ++n)
        #pragma unroll
        for (int j = 0; j < 4; ++j){
          float v = sa[q][n][j] * kScl;
          const bool ok = (mm >> (n * 16 + lk * 4 + j)) & 1ull;
          v = ok ? v : kNEG;
          sa[q][n][j] = v;
          vmax = fmaxf(vmax, v);
        }
      vmax = fmaxf(vmax, __shfl_xor(vmax, 16));
      vmax = fmaxf(vmax, __shfl_xor(vmax, 32));
      const float mn  = fmaxf(m2[q], vmax);
      const float esc = fexp2(m2[q] - mn);
      m2[q] = mn;
      float s = 0.f;
      #pragma unroll
      for (int n = 0; n < 4; ++n){
        float p0 = fexp2(sa[q][n][0] - mn), p1 = fexp2(sa[q][n][1] - mn);
        float p2 = fexp2(sa[q][n][2] - mn), p3 = fexp2(sa[q][n][3] - mn);
        s += (p0 + p1) + (p2 + p3);
        const unsigned long long pw =
            (unsigned long long)f2b(p0)        | ((unsigned long long)f2b(p1) << 16) |
            ((unsigned long long)f2b(p2) << 32) | ((unsigned long long)f2b(p3) << 48);
        const int slot = 2 * n + (lk >> 1);
        char* pb = (char*)Pw + (q * 16 + lr) * 128 + (((slot ^ lr) & 7) << 4) + ((lk & 1) << 3);
        *(unsigned long long*)pb = pw;
      }
      s += __shfl_xor(s, 16);
      s += __shfl_xor(s, 32);
      lsum[q] = lsum[q] * esc + s;
      // rescale accO rows (row lk*4+j -> state lives in lane lk*4+j)
      #pragma unroll
      for (int j = 0; j < 4; ++j){
        const float e = __shfl(esc, lk * 4 + j);
        #pragma unroll
        for (int dd = 0; dd < 4; ++dd) accO[q][dd][j] *= e;
      }
    }
    // PV: O[qrow, d] += mfma(A=P, B=V^T)
    #pragma unroll
    for (int kk = 0; kk < 2; ++kk){
      bf16x8 pf[2], vf[4];
      #pragma unroll
      for (int q = 0; q < 2; ++q)
        pf[q] = ld_swz(Pw, q * 16 + lr, kk * 4 + lk);
      #pragma unroll
      for (int dd = 0; dd < 4; ++dd)
        vf[dd] = ld_swz(Vs[cur], dd * 16 + lr, kk * 4 + lk);
      #pragma unroll
      for (int q = 0; q < 2; ++q)
        #pragma unroll
        for (int dd = 0; dd < 4; ++dd)
          accO[q][dd] = __builtin_amdgcn_mfma_f32_16x16x32_bf16(pf[q], vf[dd], accO[q][dd], 0, 0, 0);
    }
    mb0 = mbn0; mb1 = mbn1;
    __syncthreads();   // drains staging vmcnt + protects buffer flip
    cur ^= 1;
  }
  // epilogue
  #pragma unroll
  for (int q = 0; q < 2; ++q){
    #pragma unroll
    for (int j = 0; j < 4; ++j){
      const float inv = 1.0f / __shfl(lsum[q], lk * 4 + j);
      const int row = qbase + q * 16 + lk * 4 + j;
      #pragma unroll
      for (int dd = 0; dd < 4; ++dd)
        O[hoff + (size_t)row * 64 + dd * 16 + lr] = f2b(accO[q][dd][j] * inv);
    }
  }
}

// ---------------- fused add + LayerNorm (writes f32 residual + optional bf16) ----------------
__global__ __launch_bounds__(256) void add_ln_kern(const float* __restrict__ X,
                                                   const float* __restrict__ R,
                                                   const float* __restrict__ g,
                                                   const float* __restrict__ be,
                                                   float* __restrict__ Yf,
                                                   unsigned short* __restrict__ Yb){
  const int row = blockIdx.x;
  const int tid = threadIdx.x;
  const float4 xv = ((const float4*)(X + (size_t)row * kD))[tid];
  const float4 rv = ((const float4*)(R + (size_t)row * kD))[tid];
  const float a0 = xv.x + rv.x, a1 = xv.y + rv.y, a2 = xv.z + rv.z, a3 = xv.w + rv.w;
  float s = a0 + a1 + a2 + a3;
  float q = a0*a0 + a1*a1 + a2*a2 + a3*a3;
  #pragma unroll
  for (int d = 1; d < 64; d <<= 1){ s += __shfl_xor(s, d); q += __shfl_xor(q, d); }
  __shared__ float red[8];
  const int wave = tid >> 6, lane = tid & 63;
  if (lane == 0){ red[wave] = s; red[4 + wave] = q; }
  __syncthreads();
  s = red[0] + red[1] + red[2] + red[3];
  q = red[4] + red[5] + red[6] + red[7];
  const float mu   = s * (1.0f / kD);
  const float var  = q * (1.0f / kD) - mu * mu;
  const float rstd = rsqrtf(var + 1e-5f);
  const float4 gv = ((const float4*)g)[tid];
  const float4 bv = ((const float4*)be)[tid];
  const float y0 = (a0 - mu) * rstd * gv.x + bv.x;
  const float y1 = (a1 - mu) * rstd * gv.y + bv.y;
  const float y2 = (a2 - mu) * rstd * gv.z + bv.z;
  const float y3 = (a3 - mu) * rstd * gv.w + bv.w;
  ((float4*)(Yf + (size_t)row * kD))[tid] = make_float4(y0, y1, y2, y3);
  if (Yb)
    ((ushort4*)(Yb + (size_t)row * kD))[tid] = make_ushort4(f2b(y0), f2b(y1), f2b(y2), f2b(y3));
}

} // namespace

extern "C" void kernel_launch(void* const* d_in, const int* in_sizes, int n_in,
                              void* d_out, int out_size, void* d_ws, size_t ws_size,
                              hipStream_t stream){
  (void)in_sizes; (void)n_in; (void)out_size;
  const float* x   = (const float*)d_in[0];
  const int*   mask= (const int*)d_in[1];
  const float* Wq  = (const float*)d_in[2];  const float* bq  = (const float*)d_in[3];
  const float* Wk  = (const float*)d_in[4];  const float* bk  = (const float*)d_in[5];
  const float* Wv  = (const float*)d_in[6];  const float* bv  = (const float*)d_in[7];
  const float* Wo  = (const float*)d_in[8];  const float* bo  = (const float*)d_in[9];
  const float* W1  = (const float*)d_in[10]; const float* b1  = (const float*)d_in[11];
  const float* W2  = (const float*)d_in[12]; const float* b2  = (const float*)d_in[13];
  const float* g1  = (const float*)d_in[14]; const float* be1 = (const float*)d_in[15];
  const float* g2  = (const float*)d_in[16]; const float* be2 = (const float*)d_in[17];

  char* ws = (char*)d_ws;
  const size_t MB = 1024 * 1024;
  if (ws_size < 96 * MB) return;   // need 96 MB of scratch

  unsigned short* WqT = (unsigned short*)(ws + 0 * MB);   // 2 MB each
  unsigned short* WkT = (unsigned short*)(ws + 2 * MB);
  unsigned short* WvT = (unsigned short*)(ws + 4 * MB);
  unsigned short* WoT = (unsigned short*)(ws + 6 * MB);
  unsigned short* W1T = (unsigned short*)(ws + 8 * MB);   // 8 MB
  unsigned short* W2T = (unsigned short*)(ws + 16 * MB);  // 8 MB
  unsigned short* xb  = (unsigned short*)(ws + 24 * MB);  // 8 MB
  unsigned short* qb  = (unsigned short*)(ws + 32 * MB);  // 8 MB
  unsigned short* kb  = (unsigned short*)(ws + 40 * MB);  // 8 MB
  unsigned short* vb  = (unsigned short*)(ws + 48 * MB);  // 8 MB
  unsigned short* vt  = (unsigned short*)(ws + 56 * MB);  // 8 MB
  unsigned short* av  = (unsigned short*)(ws + 64 * MB);  // 8 MB
  // aliased regions (lifetimes verified):
  float* attn         = (float*)(ws + 24 * MB);           // 16 MB over xb+qb (dead)
  float* y32          = (float*)(ws + 40 * MB);           // 16 MB over kb+vb (dead)
  unsigned short* yb  = (unsigned short*)(ws + 56 * MB);  //  8 MB over vt   (dead)
  unsigned short* hb  = (unsigned short*)(ws + 64 * MB);  // 32 MB over av   (dead)
  float* ffo          = (float*)(ws + 24 * MB);           // 16 MB over attn (dead)
  unsigned long long* mbits = (unsigned long long*)(ws + 72 * MB); // 512 KB, dead before hb written

  dim3 blk(256);
  wtrans_kern<<<dim3(32, 32),  blk, 0, stream>>>(Wq, WqT, 1024, 1024);
  wtrans_kern<<<dim3(32, 32),  blk, 0, stream>>>(Wk, WkT, 1024, 1024);
  wtrans_kern<<<dim3(32, 32),  blk, 0, stream>>>(Wv, WvT, 1024, 1024);
  wtrans_kern<<<dim3(32, 32),  blk, 0, stream>>>(Wo, WoT, 1024, 1024);
  wtrans_kern<<<dim3(128, 32), blk, 0, stream>>>(W1, W1T, 1024, 4096);
  wtrans_kern<<<dim3(32, 128), blk, 0, stream>>>(W2, W2T, 4096, 1024);
  cvt_bf16_kern<<<dim3(kTOK * kD / 1024), blk, 0, stream>>>(x, xb);
  maskbits_kern<<<dim3(kS * 32 / 4), blk, 0, stream>>>(mask, mbits);

  gemm_bt_kern<1,0><<<dim3(8, 32), blk, 0, stream>>>(xb, WqT, bq, qb, 4096, 1024, 1024);
  gemm_bt_kern<1,0><<<dim3(8, 32), blk, 0, stream>>>(xb, WkT, bk, kb, 4096, 1024, 1024);
  gemm_bt_kern<1,0><<<dim3(8, 32), blk, 0, stream>>>(xb, WvT, bv, vb, 4096, 1024, 1024);

  vtrans_kern<<<dim3(32, 32), blk, 0, stream>>>(vb, vt);
  attn_kern<<<dim3(16, 32), blk, 0, stream>>>(qb, kb, vt, mbits, av);

  gemm_bt_kern<0,0><<<dim3(8, 32), blk, 0, stream>>>(av, WoT, bo, attn, 4096, 1024, 1024);
  add_ln_kern<<<dim3(4096), blk, 0, stream>>>(x, attn, g1, be1, y32, yb);

  gemm_bt_kern<1,1><<<dim3(32, 32), blk, 0, stream>>>(yb, W1T, b1, hb, 4096, 4096, 1024);
  gemm_bt_kern<0,0><<<dim3(8, 32), blk, 0, stream>>>(hb, W2T, b2, ffo, 4096, 1024, 4096);
  add_ln_kern<<<dim3(4096), blk, 0, stream>>>(y32, ffo, g2, be2, (float*)d_out, nullptr);
}

// Round 3
// 345.456 us; speedup vs baseline: 1.4467x; 1.2150x over previous
//
#include <hip/hip_runtime.h>
#include <cstdint>
#include <cstddef>

namespace {

constexpr int kS  = 2048;   // sequence
constexpr int kD  = 1024;   // model dim
constexpr int kHD = 64;     // head dim
constexpr int kTOK = 4096;  // B * S rows

typedef float f32x4 __attribute__((ext_vector_type(4)));
typedef __bf16 bf16x8 __attribute__((ext_vector_type(8)));
typedef unsigned short u16x8 __attribute__((ext_vector_type(8)));

__device__ __forceinline__ unsigned short f2b(float f){
  unsigned int u = __builtin_bit_cast(unsigned int, f);
  u += 0x7fffu + ((u >> 16) & 1u);      // RNE
  return (unsigned short)(u >> 16);
}

__device__ __forceinline__ bf16x8 ldfrag(const unsigned short* p){
  return __builtin_bit_cast(bf16x8, *(const u16x8*)p);
}

__device__ __forceinline__ float fexp2(float x){
#if __has_builtin(__builtin_amdgcn_exp2f)
  return __builtin_amdgcn_exp2f(x);
#else
  return exp2f(x);
#endif
}

__device__ __forceinline__ void gl_lds16(const void* g, void* l){
  // async global->LDS, 16B per lane; LDS dest is wave-uniform base + lane*16
  __builtin_amdgcn_global_load_lds(
      (__attribute__((address_space(1))) void*)(void*)g,
      (__attribute__((address_space(3))) void*)l, 16, 0, 0);
}

// swizzled 16B fragment read from a 64-col bf16 tile: slot in [0,8)
__device__ __forceinline__ bf16x8 ld_swz(const unsigned short* tile, int row, int slot){
  return ldfrag(tile + row * 64 + (((slot ^ row) & 7) << 3));
}

// Stage one 64-seq-row K tile from the fused QKV buffer (head-block mapping):
// seq row s lives at Kg[(s>>4)*3072 + (s&15)*64 + d]. Source column pre-swizzled.
__device__ __forceinline__ void stageK(const unsigned short* Kg, unsigned short* lds,
                                       int wave, int lane, int t0){
  #pragma unroll
  for (int i = 0; i < 2; ++i){
    const int lin = i * 4096 + wave * 1024 + lane * 16;  // byte offset in tile
    const int r = lin >> 7;                               // tile row
    const int sl = (lin >> 4) & 7;                        // 16B slot
    const int sabs = t0 + r;
    gl_lds16(Kg + (size_t)(sabs >> 4) * 3072 + (sabs & 15) * 64 + (((sl ^ r) & 7) << 3),
             (char*)lds + i * 4096 + wave * 1024);
  }
}

// Stage a 64x64 slice of Vt [64][kS] (cols t0..t0+64), source-swizzled.
__device__ __forceinline__ void stageV(const unsigned short* Vh, unsigned short* lds,
                                       int wave, int lane, int t0){
  #pragma unroll
  for (int i = 0; i < 2; ++i){
    const int lin = i * 4096 + wave * 1024 + lane * 16;
    const int r = lin >> 7;
    const int sl = (lin >> 4) & 7;
    gl_lds16(Vh + (size_t)r * kS + t0 + (((sl ^ r) & 7) << 3),
             (char*)lds + i * 4096 + wave * 1024);
  }
}

// ---------------- f32 -> bf16 elementwise ----------------
__global__ __launch_bounds__(256) void cvt_bf16_kern(const float* __restrict__ X,
                                                     unsigned short* __restrict__ Y){
  int i = blockIdx.x * 256 + threadIdx.x;
  float4 v = ((const float4*)X)[i];
  ((ushort4*)Y)[i] = make_ushort4(f2b(v.x), f2b(v.y), f2b(v.z), f2b(v.w));
}

// ---------------- mask -> bit-packed u64, PERMUTED so lane bits are contiguous ----
// ballot bit b holds mask of key k(b) = ((b>>2)&3)*16 + ((b>>4)&3)*4 + (b&3)
// => key n*16+lk*4+j sits at bit lk*16 + n*4 + j.
__global__ __launch_bounds__(256) void maskbits_kern(const int* __restrict__ mask,
                                                     unsigned long long* __restrict__ mb){
  const int gw   = (blockIdx.x * 256 + threadIdx.x) >> 6;   // global wave id
  const int lane = threadIdx.x & 63;
  const int row  = gw >> 5, word = gw & 31;
  const int key  = ((lane >> 2) & 3) * 16 + ((lane >> 4) & 3) * 4 + (lane & 3);
  const int m = mask[(size_t)row * kS + word * 64 + key];
  const unsigned long long b = __ballot(m != 0);
  if (lane == 0) mb[(size_t)row * 32 + word] = b;
}

// ---------------- concat 3 bias vectors (1024 each) into one 3072 ----------------
__global__ __launch_bounds__(256) void catbias_kern(const float* __restrict__ a,
                                                    const float* __restrict__ b,
                                                    const float* __restrict__ c,
                                                    float* __restrict__ o){
  int i = blockIdx.x * 256 + threadIdx.x;
  float v = (i < 1024) ? a[i] : ((i < 2048) ? b[i - 1024] : c[i - 2048]);
  o[i] = v;
}

// ---------------- W[K,N] f32 -> Wt[N,K] bf16 (transpose+convert) ----------------
__global__ __launch_bounds__(256) void wtrans_kern(const float* __restrict__ W,
                                                   unsigned short* __restrict__ Wt,
                                                   int K, int N){
  __shared__ float t[32][33];
  int n0 = blockIdx.x * 32, k0 = blockIdx.y * 32;
  int tx = threadIdx.x & 31, ty = threadIdx.x >> 5;   // ty in [0,8)
  #pragma unroll
  for (int i = 0; i < 32; i += 8)
    t[ty + i][tx] = W[(size_t)(k0 + ty + i) * N + n0 + tx];
  __syncthreads();
  #pragma unroll
  for (int i = 0; i < 32; i += 8)
    Wt[(size_t)(n0 + ty + i) * K + k0 + tx] = f2b(t[tx][ty + i]);
}

// ---------------- V slice of fused QKV -> Vt [bh][64][kS] (bf16 transpose) -------
__global__ __launch_bounds__(256) void vtrans_kern(const unsigned short* __restrict__ QKV,
                                                   unsigned short* __restrict__ Vt){
  __shared__ unsigned short t[64][65];
  int bh = blockIdx.y, s0 = blockIdx.x * 64;
  const int rowbase = (bh >> 4) * 2048 + (bh & 15) * 128;
  const unsigned short* Vg = QKV + (size_t)rowbase * 3072 + 2048;
  unsigned short* Vth = Vt + (size_t)bh * kHD * kS;
  int tx = threadIdx.x & 63, ty = threadIdx.x >> 6;   // ty in [0,4)
  #pragma unroll
  for (int i = 0; i < 64; i += 4){
    const int s = s0 + ty + i;
    t[ty + i][tx] = Vg[(size_t)(s >> 4) * 3072 + (s & 15) * 64 + tx];
  }
  __syncthreads();
  #pragma unroll
  for (int i = 0; i < 64; i += 4)
    Vth[(size_t)(ty + i) * kS + s0 + tx] = t[tx][ty + i];
}

// ---------------- GEMM: C[M,N] = A[M,K]*Bt[N,K]^T + bias (bf16 in, f32 acc) ------
template <int OUT_BF16, int ACT_GELU>
__global__ __launch_bounds__(256) void gemm_bt_kern(const unsigned short* __restrict__ A,
                                                    const unsigned short* __restrict__ Bt,
                                                    const float* __restrict__ bias,
                                                    void* __restrict__ C,
                                                    int M, int N, int K){
  __shared__ unsigned short As[128 * 32];
  __shared__ unsigned short Bs[128 * 32];
  const int tid  = threadIdx.x;
  const int wave = tid >> 6, lane = tid & 63;
  const int wr = wave >> 1, wc = wave & 1;
  const int m0 = blockIdx.y << 7, n0 = blockIdx.x << 7;
  const int lr = lane & 15, lk = lane >> 4;
  const int ch0 = wave * 2, ch1 = wave * 2 + 1;
  const int sr0 = ch0 * 16 + (lane >> 2), sr1 = ch1 * 16 + (lane >> 2);
  const int sc  = (lane & 3) * 8;
  f32x4 acc[4][4] = {};
  for (int k0 = 0; k0 < K; k0 += 32){
    __syncthreads();
    gl_lds16(A  + (size_t)(m0 + sr0) * K + k0 + sc, As + ch0 * 512);
    gl_lds16(A  + (size_t)(m0 + sr1) * K + k0 + sc, As + ch1 * 512);
    gl_lds16(Bt + (size_t)(n0 + sr0) * K + k0 + sc, Bs + ch0 * 512);
    gl_lds16(Bt + (size_t)(n0 + sr1) * K + k0 + sc, Bs + ch1 * 512);
    __syncthreads();
    bf16x8 af[4], bfr[4];
    #pragma unroll
    for (int m = 0; m < 4; ++m)
      af[m] = ldfrag(&As[(wr * 64 + m * 16 + lr) * 32 + lk * 8]);
    #pragma unroll
    for (int n = 0; n < 4; ++n)
      bfr[n] = ldfrag(&Bs[(wc * 64 + n * 16 + lr) * 32 + lk * 8]);
    #pragma unroll
    for (int m = 0; m < 4; ++m)
      #pragma unroll
      for (int n = 0; n < 4; ++n)
        acc[m][n] = __builtin_amdgcn_mfma_f32_16x16x32_bf16(af[m], bfr[n], acc[m][n], 0, 0, 0);
  }
  #pragma unroll
  for (int n = 0; n < 4; ++n){
    const int col = n0 + wc * 64 + n * 16 + lr;
    const float bv = bias[col];
    #pragma unroll
    for (int m = 0; m < 4; ++m){
      #pragma unroll
      for (int j = 0; j < 4; ++j){
        const int row = m0 + wr * 64 + m * 16 + lk * 4 + j;
        float v = acc[m][n][j] + bv;
        if (ACT_GELU) v = 0.5f * v * (1.0f + erff(v * 0.70710678118654752f));
        if (OUT_BF16) ((unsigned short*)C)[(size_t)row * N + col] = f2b(v);
        else          ((float*)C)[(size_t)row * N + col] = v;
      }
    }
  }
}

// ---------------- flash attention v3: no-max softmax (bounded scores), QBLK=64 ---
// grid (S/64, BH); 4 waves x 16 q-rows. K read from fused QKV, V from Vt.
__global__ __launch_bounds__(256) void attn_kern(const unsigned short* __restrict__ QKV,
                                                 const unsigned short* __restrict__ Vt,
                                                 const unsigned long long* __restrict__ mbits,
                                                 unsigned short* __restrict__ O){
  __shared__ unsigned short Ks[2][64 * 64];
  __shared__ unsigned short Vs[2][64 * 64];     // [d][t], swizzled
  __shared__ unsigned short Ps[4][16 * 64];     // per-wave P [qrow][key], swizzled
  const int tid = threadIdx.x;
  const int wave = tid >> 6, lane = tid & 63;
  const int lr = lane & 15, lk = lane >> 4;
  const int bh = blockIdx.y;
  const int rowbase = (bh >> 4) * 2048 + (bh & 15) * 128;
  const unsigned short* Qg = QKV + (size_t)rowbase * 3072;
  const unsigned short* Kg = Qg + 1024;
  const unsigned short* Vh = Vt + (size_t)bh * kHD * kS;
  const int qbase = blockIdx.x * 64 + wave * 16;
  constexpr float kScl = 0.18033688011112042f;  // 0.125 * log2(e)

  // Q as MFMA B-fragment (col = qrow = lr), registers
  bf16x8 qf[2];
  { const int qr = qbase + lr;
    const unsigned short* qp = Qg + (size_t)(qr >> 4) * 3072 + (qr & 15) * 64 + lk * 8;
    qf[0] = ldfrag(qp); qf[1] = ldfrag(qp + 32); }

  f32x4 accO[4] = {};
  float lsum = 0.f;
  unsigned short* Pw = Ps[wave];
  char* Pwb = (char*)Pw + lr * 128 + ((lk & 1) << 3);
  const int lr7 = lr & 7;

  const unsigned long long* mrp = mbits + (size_t)(qbase + lr) * 32;
  unsigned long long mb = mrp[0];

  stageK(Kg, Ks[0], wave, lane, 0);
  stageV(Vh, Vs[0], wave, lane, 0);
  __syncthreads();

  int cur = 0;
  for (int t = 0; t < kS / 64; ++t){
    unsigned long long mbn = 0;
    if (t < kS / 64 - 1){
      stageK(Kg, Ks[cur ^ 1], wave, lane, (t + 1) * 64);
      stageV(Vh, Vs[cur ^ 1], wave, lane, (t + 1) * 64);
      mbn = mrp[t + 1];
    }
    // QK^T swapped: sa[n][j] = S[key = n*16 + lk*4 + j][qrow = lr]
    f32x4 sa[4] = {};
    #pragma unroll
    for (int kk = 0; kk < 2; ++kk)
      #pragma unroll
      for (int n = 0; n < 4; ++n){
        bf16x8 kf = ld_swz(Ks[cur], n * 16 + lr, kk * 4 + lk);
        sa[n] = __builtin_amdgcn_mfma_f32_16x16x32_bf16(kf, qf[kk], sa[n], 0, 0, 0);
      }
    // softmax, no max tracking (scores bounded; see round-3 analysis)
    const unsigned wb = (unsigned)(mb >> (lk * 16));
    float s = 0.f;
    #pragma unroll
    for (int n = 0; n < 4; ++n){
      float p0, p1, p2, p3;
      {
        float v0 = fexp2(sa[n][0] * kScl), v1 = fexp2(sa[n][1] * kScl);
        float v2 = fexp2(sa[n][2] * kScl), v3 = fexp2(sa[n][3] * kScl);
        const int s0 = ((int)(wb << (31 - (n * 4 + 0)))) >> 31;
        const int s1 = ((int)(wb << (31 - (n * 4 + 1)))) >> 31;
        const int s2 = ((int)(wb << (31 - (n * 4 + 2)))) >> 31;
        const int s3 = ((int)(wb << (31 - (n * 4 + 3)))) >> 31;
        p0 = __builtin_bit_cast(float, __builtin_bit_cast(int, v0) & s0);
        p1 = __builtin_bit_cast(float, __builtin_bit_cast(int, v1) & s1);
        p2 = __builtin_bit_cast(float, __builtin_bit_cast(int, v2) & s2);
        p3 = __builtin_bit_cast(float, __builtin_bit_cast(int, v3) & s3);
      }
      s += (p0 + p1) + (p2 + p3);
      unsigned r0, r1;
      asm("v_cvt_pk_bf16_f32 %0, %1, %2" : "=v"(r0) : "v"(p0), "v"(p1));
      asm("v_cvt_pk_bf16_f32 %0, %1, %2" : "=v"(r1) : "v"(p2), "v"(p3));
      *(uint2*)(Pwb + (((2 * n + (lk >> 1)) ^ lr7) << 4)) = make_uint2(r0, r1);
    }
    s += __shfl_xor(s, 16);
    s += __shfl_xor(s, 32);
    lsum += s;
    // PV: accO[dd] += P[qrows][keys] * V^T[keys][d]
    #pragma unroll
    for (int kk = 0; kk < 2; ++kk){
      bf16x8 pf = ld_swz(Pw, lr, kk * 4 + lk);
      #pragma unroll
      for (int dd = 0; dd < 4; ++dd){
        bf16x8 vfr = ld_swz(Vs[cur], dd * 16 + lr, kk * 4 + lk);
        accO[dd] = __builtin_amdgcn_mfma_f32_16x16x32_bf16(pf, vfr, accO[dd], 0, 0, 0);
      }
    }
    mb = mbn;
    __syncthreads();   // drains staging vmcnt + protects buffer flip
    cur ^= 1;
  }
  const size_t hoff = (size_t)bh * kS * kHD;
  #pragma unroll
  for (int j = 0; j < 4; ++j){
    const float inv = 1.0f / __shfl(lsum, lk * 4 + j);
    const int row = qbase + lk * 4 + j;
    #pragma unroll
    for (int dd = 0; dd < 4; ++dd)
      O[hoff + (size_t)row * 64 + dd * 16 + lr] = f2b(accO[dd][j] * inv);
  }
}

// ---------------- fused add + LayerNorm (writes f32 residual + optional bf16) ----
__global__ __launch_bounds__(256) void add_ln_kern(const float* __restrict__ X,
                                                   const float* __restrict__ R,
                                                   const float* __restrict__ g,
                                                   const float* __restrict__ be,
                                                   float* __restrict__ Yf,
                                                   unsigned short* __restrict__ Yb){
  const int row = blockIdx.x;
  const int tid = threadIdx.x;
  const float4 xv = ((const float4*)(X + (size_t)row * kD))[tid];
  const float4 rv = ((const float4*)(R + (size_t)row * kD))[tid];
  const float a0 = xv.x + rv.x, a1 = xv.y + rv.y, a2 = xv.z + rv.z, a3 = xv.w + rv.w;
  float s = a0 + a1 + a2 + a3;
  float q = a0*a0 + a1*a1 + a2*a2 + a3*a3;
  #pragma unroll
  for (int d = 1; d < 64; d <<= 1){ s += __shfl_xor(s, d); q += __shfl_xor(q, d); }
  __shared__ float red[8];
  const int wave = tid >> 6, lane = tid & 63;
  if (lane == 0){ red[wave] = s; red[4 + wave] = q; }
  __syncthreads();
  s = red[0] + red[1] + red[2] + red[3];
  q = red[4] + red[5] + red[6] + red[7];
  const float mu   = s * (1.0f / kD);
  const float var  = q * (1.0f / kD) - mu * mu;
  const float rstd = rsqrtf(var + 1e-5f);
  const float4 gv = ((const float4*)g)[tid];
  const float4 bv = ((const float4*)be)[tid];
  const float y0 = (a0 - mu) * rstd * gv.x + bv.x;
  const float y1 = (a1 - mu) * rstd * gv.y + bv.y;
  const float y2 = (a2 - mu) * rstd * gv.z + bv.z;
  const float y3 = (a3 - mu) * rstd * gv.w + bv.w;
  ((float4*)(Yf + (size_t)row * kD))[tid] = make_float4(y0, y1, y2, y3);
  if (Yb)
    ((ushort4*)(Yb + (size_t)row * kD))[tid] = make_ushort4(f2b(y0), f2b(y1), f2b(y2), f2b(y3));
}

} // namespace

extern "C" void kernel_launch(void* const* d_in, const int* in_sizes, int n_in,
                              void* d_out, int out_size, void* d_ws, size_t ws_size,
                              hipStream_t stream){
  (void)in_sizes; (void)n_in; (void)out_size;
  const float* x   = (const float*)d_in[0];
  const int*   mask= (const int*)d_in[1];
  const float* Wq  = (const float*)d_in[2];  const float* bq  = (const float*)d_in[3];
  const float* Wk  = (const float*)d_in[4];  const float* bk  = (const float*)d_in[5];
  const float* Wv  = (const float*)d_in[6];  const float* bv  = (const float*)d_in[7];
  const float* Wo  = (const float*)d_in[8];  const float* bo  = (const float*)d_in[9];
  const float* W1  = (const float*)d_in[10]; const float* b1  = (const float*)d_in[11];
  const float* W2  = (const float*)d_in[12]; const float* b2  = (const float*)d_in[13];
  const float* g1  = (const float*)d_in[14]; const float* be1 = (const float*)d_in[15];
  const float* g2  = (const float*)d_in[16]; const float* be2 = (const float*)d_in[17];

  char* ws = (char*)d_ws;
  const size_t MB = 1024 * 1024;
  if (ws_size < 96 * MB) return;   // need 96 MB of scratch

  // persistent-for-phase buffers
  unsigned short* W2T   = (unsigned short*)(ws + 0 * MB);   //  8 MB  [1024][4096]
  unsigned short* W1T   = (unsigned short*)(ws + 8 * MB);   //  8 MB  [4096][1024]
  unsigned short* WqkvT = (unsigned short*)(ws + 16 * MB);  //  6 MB  [3072][1024]
  unsigned short* WoT   = (unsigned short*)(ws + 22 * MB);  //  2 MB
  unsigned short* xb    = (unsigned short*)(ws + 24 * MB);  //  8 MB
  unsigned short* qkv   = (unsigned short*)(ws + 32 * MB);  // 24 MB  [4096][3072]
  unsigned short* vt    = (unsigned short*)(ws + 56 * MB);  //  8 MB  [32][64][2048]
  unsigned short* av    = (unsigned short*)(ws + 64 * MB);  //  8 MB
  unsigned long long* mbits = (unsigned long long*)(ws + 72 * MB);       // 512 KB
  float* bqkv           = (float*)(ws + 72 * MB + 512 * 1024);           // 12 KB
  // aliases (lifetimes checked):
  float* attnf        = (float*)(ws + 32 * MB);           // 16 MB over qkv[0:16] (dead after attn)
  float* y32          = (float*)(ws + 48 * MB);           // 16 MB over qkv[16:24]+vt (dead)
  unsigned short* yb  = (unsigned short*)(ws + 64 * MB);  //  8 MB over av (dead after Wo gemm)
  unsigned short* hb  = (unsigned short*)(ws + 16 * MB);  // 32 MB over WqkvT/WoT/xb/attnf (dead)
  float* ffo          = (float*)(ws + 72 * MB);           // 16 MB over mbits/bqkv (dead)

  dim3 blk(256);
  wtrans_kern<<<dim3(32, 32),  blk, 0, stream>>>(Wq, WqkvT,                  1024, 1024);
  wtrans_kern<<<dim3(32, 32),  blk, 0, stream>>>(Wk, WqkvT + 1024 * 1024,    1024, 1024);
  wtrans_kern<<<dim3(32, 32),  blk, 0, stream>>>(Wv, WqkvT + 2 * 1024 * 1024, 1024, 1024);
  wtrans_kern<<<dim3(32, 32),  blk, 0, stream>>>(Wo, WoT, 1024, 1024);
  wtrans_kern<<<dim3(128, 32), blk, 0, stream>>>(W1, W1T, 1024, 4096);
  wtrans_kern<<<dim3(32, 128), blk, 0, stream>>>(W2, W2T, 4096, 1024);
  cvt_bf16_kern<<<dim3(kTOK * kD / 1024), blk, 0, stream>>>(x, xb);
  maskbits_kern<<<dim3(kS * 32 / 4), blk, 0, stream>>>(mask, mbits);
  catbias_kern<<<dim3(12), blk, 0, stream>>>(bq, bk, bv, bqkv);

  // fused QKV projection: [4096][3072]
  gemm_bt_kern<1,0><<<dim3(24, 32), blk, 0, stream>>>(xb, WqkvT, bqkv, qkv, 4096, 3072, 1024);

  vtrans_kern<<<dim3(32, 32), blk, 0, stream>>>(qkv, vt);
  attn_kern<<<dim3(32, 32), blk, 0, stream>>>(qkv, vt, mbits, av);

  gemm_bt_kern<0,0><<<dim3(8, 32), blk, 0, stream>>>(av, WoT, bo, attnf, 4096, 1024, 1024);
  add_ln_kern<<<dim3(4096), blk, 0, stream>>>(x, attnf, g1, be1, y32, yb);

  gemm_bt_kern<1,1><<<dim3(32, 32), blk, 0, stream>>>(yb, W1T, b1, hb, 4096, 4096, 1024);
  gemm_bt_kern<0,0><<<dim3(8, 32), blk, 0, stream>>>(hb, W2T, b2, ffo, 4096, 1024, 4096);
  add_ln_kern<<<dim3(4096), blk, 0, stream>>>(y32, ffo, g2, be2, (float*)d_out, nullptr);
}

// Round 4
// 314.856 us; speedup vs baseline: 1.5873x; 1.0972x over previous
//
#include <hip/hip_runtime.h>
#include <cstdint>
#include <cstddef>

namespace {

constexpr int kS  = 2048;   // sequence
constexpr int kD  = 1024;   // model dim
constexpr int kHD = 64;     // head dim
constexpr int kTOK = 4096;  // B * S rows

typedef float f32x4 __attribute__((ext_vector_type(4)));
typedef __bf16 bf16x8 __attribute__((ext_vector_type(8)));
typedef unsigned short u16x8 __attribute__((ext_vector_type(8)));

__device__ __forceinline__ unsigned short f2b(float f){
  unsigned int u = __builtin_bit_cast(unsigned int, f);
  u += 0x7fffu + ((u >> 16) & 1u);      // RNE
  return (unsigned short)(u >> 16);
}

__device__ __forceinline__ float b2f(unsigned short u){
  return __builtin_bit_cast(float, (unsigned)u << 16);
}

__device__ __forceinline__ bf16x8 ldfrag(const unsigned short* p){
  return __builtin_bit_cast(bf16x8, *(const u16x8*)p);
}

__device__ __forceinline__ float fexp2(float x){
#if __has_builtin(__builtin_amdgcn_exp2f)
  return __builtin_amdgcn_exp2f(x);
#else
  return exp2f(x);
#endif
}

__device__ __forceinline__ void gl_lds16(const void* g, void* l){
  // async global->LDS, 16B per lane; LDS dest is wave-uniform base + lane*16
  __builtin_amdgcn_global_load_lds(
      (__attribute__((address_space(1))) void*)(void*)g,
      (__attribute__((address_space(3))) void*)l, 16, 0, 0);
}

// swizzled 16B fragment read from a 64-col bf16 tile: slot in [0,8)
__device__ __forceinline__ bf16x8 ld_swz(const unsigned short* tile, int row, int slot){
  return ldfrag(tile + row * 64 + (((slot ^ row) & 7) << 3));
}

// Stage one 64-seq-row K tile from the fused QKV buffer (head-block mapping):
// seq row s lives at Kg[(s>>4)*3072 + (s&15)*64 + d]. Source column pre-swizzled.
__device__ __forceinline__ void stageK(const unsigned short* Kg, unsigned short* lds,
                                       int wave, int lane, int t0){
  #pragma unroll
  for (int i = 0; i < 2; ++i){
    const int lin = i * 4096 + wave * 1024 + lane * 16;  // byte offset in tile
    const int r = lin >> 7;                               // tile row
    const int sl = (lin >> 4) & 7;                        // 16B slot
    const int sabs = t0 + r;
    gl_lds16(Kg + (size_t)(sabs >> 4) * 3072 + (sabs & 15) * 64 + (((sl ^ r) & 7) << 3),
             (char*)lds + i * 4096 + wave * 1024);
  }
}

// Stage a 64x64 slice of Vt [64][kS] (cols t0..t0+64), source-swizzled.
__device__ __forceinline__ void stageV(const unsigned short* Vh, unsigned short* lds,
                                       int wave, int lane, int t0){
  #pragma unroll
  for (int i = 0; i < 2; ++i){
    const int lin = i * 4096 + wave * 1024 + lane * 16;
    const int r = lin >> 7;
    const int sl = (lin >> 4) & 7;
    gl_lds16(Vh + (size_t)r * kS + t0 + (((sl ^ r) & 7) << 3),
             (char*)lds + i * 4096 + wave * 1024);
  }
}

// ---------------- f32 -> bf16 elementwise ----------------
__global__ __launch_bounds__(256) void cvt_bf16_kern(const float* __restrict__ X,
                                                     unsigned short* __restrict__ Y){
  int i = blockIdx.x * 256 + threadIdx.x;
  float4 v = ((const float4*)X)[i];
  ((ushort4*)Y)[i] = make_ushort4(f2b(v.x), f2b(v.y), f2b(v.z), f2b(v.w));
}

// ---------------- mask -> bit-packed u64, PERMUTED so lane bits are contiguous ----
__global__ __launch_bounds__(256) void maskbits_kern(const int* __restrict__ mask,
                                                     unsigned long long* __restrict__ mb){
  const int gw   = (blockIdx.x * 256 + threadIdx.x) >> 6;   // global wave id
  const int lane = threadIdx.x & 63;
  const int row  = gw >> 5, word = gw & 31;
  const int key  = ((lane >> 2) & 3) * 16 + ((lane >> 4) & 3) * 4 + (lane & 3);
  const int m = mask[(size_t)row * kS + word * 64 + key];
  const unsigned long long b = __ballot(m != 0);
  if (lane == 0) mb[(size_t)row * 32 + word] = b;
}

// ---------------- concat 3 bias vectors (1024 each) into one 3072 ----------------
__global__ __launch_bounds__(256) void catbias_kern(const float* __restrict__ a,
                                                    const float* __restrict__ b,
                                                    const float* __restrict__ c,
                                                    float* __restrict__ o){
  int i = blockIdx.x * 256 + threadIdx.x;
  float v = (i < 1024) ? a[i] : ((i < 2048) ? b[i - 1024] : c[i - 2048]);
  o[i] = v;
}

// ---------------- W[K,N] f32 -> Wt[N,K] bf16 (transpose+convert) ----------------
__global__ __launch_bounds__(256) void wtrans_kern(const float* __restrict__ W,
                                                   unsigned short* __restrict__ Wt,
                                                   int K, int N){
  __shared__ float t[32][33];
  int n0 = blockIdx.x * 32, k0 = blockIdx.y * 32;
  int tx = threadIdx.x & 31, ty = threadIdx.x >> 5;   // ty in [0,8)
  #pragma unroll
  for (int i = 0; i < 32; i += 8)
    t[ty + i][tx] = W[(size_t)(k0 + ty + i) * N + n0 + tx];
  __syncthreads();
  #pragma unroll
  for (int i = 0; i < 32; i += 8)
    Wt[(size_t)(n0 + ty + i) * K + k0 + tx] = f2b(t[tx][ty + i]);
}

// ---------------- V slice of fused QKV -> Vt [bh][64][kS] (bf16 transpose) -------
__global__ __launch_bounds__(256) void vtrans_kern(const unsigned short* __restrict__ QKV,
                                                   unsigned short* __restrict__ Vt){
  __shared__ unsigned short t[64][65];
  int bh = blockIdx.y, s0 = blockIdx.x * 64;
  const int rowbase = (bh >> 4) * 2048 + (bh & 15) * 128;
  const unsigned short* Vg = QKV + (size_t)rowbase * 3072 + 2048;
  unsigned short* Vth = Vt + (size_t)bh * kHD * kS;
  int tx = threadIdx.x & 63, ty = threadIdx.x >> 6;   // ty in [0,4)
  #pragma unroll
  for (int i = 0; i < 64; i += 4){
    const int s = s0 + ty + i;
    t[ty + i][tx] = Vg[(size_t)(s >> 4) * 3072 + (s & 15) * 64 + tx];
  }
  __syncthreads();
  #pragma unroll
  for (int i = 0; i < 64; i += 4)
    Vth[(size_t)(ty + i) * kS + s0 + tx] = t[tx][ty + i];
}

// ---------------- GEMM: C = A[M,K]*Bt[N,K]^T (+bias), optional split-K ----------
// XCD-aware bijective block swizzle (requires gridDim.x*gridDim.y % 8 == 0).
// SPLITK>1: blockIdx.z owns K-chunk, writes partial (no bias) at C + z*M*N.
template <int OUT_BF16, int ACT_GELU, int SPLITK>
__global__ __launch_bounds__(256) void gemm_bt_kern(const unsigned short* __restrict__ A,
                                                    const unsigned short* __restrict__ Bt,
                                                    const float* __restrict__ bias,
                                                    void* __restrict__ C,
                                                    int M, int N, int K){
  __shared__ unsigned short As[128 * 32];
  __shared__ unsigned short Bs[128 * 32];
  int bid = blockIdx.y * gridDim.x + blockIdx.x;
  const int nwg = gridDim.x * gridDim.y;
  bid = (bid & 7) * (nwg >> 3) + (bid >> 3);            // T1 XCD swizzle
  const unsigned bx = (unsigned)bid % gridDim.x;
  const unsigned by = (unsigned)bid / gridDim.x;
  const int tid  = threadIdx.x;
  const int wave = tid >> 6, lane = tid & 63;
  const int wr = wave >> 1, wc = wave & 1;
  const int m0 = by << 7, n0 = bx << 7;
  const int lr = lane & 15, lk = lane >> 4;
  const int ch0 = wave * 2, ch1 = wave * 2 + 1;
  const int sr0 = ch0 * 16 + (lane >> 2), sr1 = ch1 * 16 + (lane >> 2);
  const int sc  = (lane & 3) * 8;
  const int kz   = K / SPLITK;
  const int kbeg = blockIdx.z * kz, kend = kbeg + kz;
  f32x4 acc[4][4] = {};
  for (int k0 = kbeg; k0 < kend; k0 += 32){
    __syncthreads();
    gl_lds16(A  + (size_t)(m0 + sr0) * K + k0 + sc, As + ch0 * 512);
    gl_lds16(A  + (size_t)(m0 + sr1) * K + k0 + sc, As + ch1 * 512);
    gl_lds16(Bt + (size_t)(n0 + sr0) * K + k0 + sc, Bs + ch0 * 512);
    gl_lds16(Bt + (size_t)(n0 + sr1) * K + k0 + sc, Bs + ch1 * 512);
    __syncthreads();
    bf16x8 af[4], bfr[4];
    #pragma unroll
    for (int m = 0; m < 4; ++m)
      af[m] = ldfrag(&As[(wr * 64 + m * 16 + lr) * 32 + lk * 8]);
    #pragma unroll
    for (int n = 0; n < 4; ++n)
      bfr[n] = ldfrag(&Bs[(wc * 64 + n * 16 + lr) * 32 + lk * 8]);
    #pragma unroll
    for (int m = 0; m < 4; ++m)
      #pragma unroll
      for (int n = 0; n < 4; ++n)
        acc[m][n] = __builtin_amdgcn_mfma_f32_16x16x32_bf16(af[m], bfr[n], acc[m][n], 0, 0, 0);
  }
  unsigned short* Cb = (unsigned short*)C + (SPLITK > 1 ? (size_t)blockIdx.z * M * N : 0);
  float*          Cf = (float*)C          + (SPLITK > 1 ? (size_t)blockIdx.z * M * N : 0);
  #pragma unroll
  for (int n = 0; n < 4; ++n){
    const int col = n0 + wc * 64 + n * 16 + lr;
    const float bv = (SPLITK == 1) ? bias[col] : 0.0f;
    #pragma unroll
    for (int m = 0; m < 4; ++m){
      #pragma unroll
      for (int j = 0; j < 4; ++j){
        const int row = m0 + wr * 64 + m * 16 + lk * 4 + j;
        float v = acc[m][n][j] + bv;
        if (ACT_GELU) v = 0.5f * v * (1.0f + erff(v * 0.70710678118654752f));
        if (OUT_BF16) Cb[(size_t)row * N + col] = f2b(v);
        else          Cf[(size_t)row * N + col] = v;
      }
    }
  }
}

// ---------------- flash attention v3: no-max softmax (bounded scores), QBLK=64 ---
__global__ __launch_bounds__(256) void attn_kern(const unsigned short* __restrict__ QKV,
                                                 const unsigned short* __restrict__ Vt,
                                                 const unsigned long long* __restrict__ mbits,
                                                 unsigned short* __restrict__ O){
  __shared__ unsigned short Ks[2][64 * 64];
  __shared__ unsigned short Vs[2][64 * 64];     // [d][t], swizzled
  __shared__ unsigned short Ps[4][16 * 64];     // per-wave P [qrow][key], swizzled
  const int tid = threadIdx.x;
  const int wave = tid >> 6, lane = tid & 63;
  const int lr = lane & 15, lk = lane >> 4;
  const int bh = blockIdx.y;
  const int rowbase = (bh >> 4) * 2048 + (bh & 15) * 128;
  const unsigned short* Qg = QKV + (size_t)rowbase * 3072;
  const unsigned short* Kg = Qg + 1024;
  const unsigned short* Vh = Vt + (size_t)bh * kHD * kS;
  const int qbase = blockIdx.x * 64 + wave * 16;
  constexpr float kScl = 0.18033688011112042f;  // 0.125 * log2(e)

  bf16x8 qf[2];
  { const int qr = qbase + lr;
    const unsigned short* qp = Qg + (size_t)(qr >> 4) * 3072 + (qr & 15) * 64 + lk * 8;
    qf[0] = ldfrag(qp); qf[1] = ldfrag(qp + 32); }

  f32x4 accO[4] = {};
  float lsum = 0.f;
  unsigned short* Pw = Ps[wave];
  char* Pwb = (char*)Pw + lr * 128 + ((lk & 1) << 3);
  const int lr7 = lr & 7;

  const unsigned long long* mrp = mbits + (size_t)(qbase + lr) * 32;
  unsigned long long mb = mrp[0];

  stageK(Kg, Ks[0], wave, lane, 0);
  stageV(Vh, Vs[0], wave, lane, 0);
  __syncthreads();

  int cur = 0;
  for (int t = 0; t < kS / 64; ++t){
    unsigned long long mbn = 0;
    if (t < kS / 64 - 1){
      stageK(Kg, Ks[cur ^ 1], wave, lane, (t + 1) * 64);
      stageV(Vh, Vs[cur ^ 1], wave, lane, (t + 1) * 64);
      mbn = mrp[t + 1];
    }
    f32x4 sa[4] = {};
    #pragma unroll
    for (int kk = 0; kk < 2; ++kk)
      #pragma unroll
      for (int n = 0; n < 4; ++n){
        bf16x8 kf = ld_swz(Ks[cur], n * 16 + lr, kk * 4 + lk);
        sa[n] = __builtin_amdgcn_mfma_f32_16x16x32_bf16(kf, qf[kk], sa[n], 0, 0, 0);
      }
    const unsigned wb = (unsigned)(mb >> (lk * 16));
    float s = 0.f;
    #pragma unroll
    for (int n = 0; n < 4; ++n){
      float p0, p1, p2, p3;
      {
        float v0 = fexp2(sa[n][0] * kScl), v1 = fexp2(sa[n][1] * kScl);
        float v2 = fexp2(sa[n][2] * kScl), v3 = fexp2(sa[n][3] * kScl);
        const int s0 = ((int)(wb << (31 - (n * 4 + 0)))) >> 31;
        const int s1 = ((int)(wb << (31 - (n * 4 + 1)))) >> 31;
        const int s2 = ((int)(wb << (31 - (n * 4 + 2)))) >> 31;
        const int s3 = ((int)(wb << (31 - (n * 4 + 3)))) >> 31;
        p0 = __builtin_bit_cast(float, __builtin_bit_cast(int, v0) & s0);
        p1 = __builtin_bit_cast(float, __builtin_bit_cast(int, v1) & s1);
        p2 = __builtin_bit_cast(float, __builtin_bit_cast(int, v2) & s2);
        p3 = __builtin_bit_cast(float, __builtin_bit_cast(int, v3) & s3);
      }
      s += (p0 + p1) + (p2 + p3);
      unsigned r0, r1;
      asm("v_cvt_pk_bf16_f32 %0, %1, %2" : "=v"(r0) : "v"(p0), "v"(p1));
      asm("v_cvt_pk_bf16_f32 %0, %1, %2" : "=v"(r1) : "v"(p2), "v"(p3));
      *(uint2*)(Pwb + (((2 * n + (lk >> 1)) ^ lr7) << 4)) = make_uint2(r0, r1);
    }
    s += __shfl_xor(s, 16);
    s += __shfl_xor(s, 32);
    lsum += s;
    #pragma unroll
    for (int kk = 0; kk < 2; ++kk){
      bf16x8 pf = ld_swz(Pw, lr, kk * 4 + lk);
      #pragma unroll
      for (int dd = 0; dd < 4; ++dd){
        bf16x8 vfr = ld_swz(Vs[cur], dd * 16 + lr, kk * 4 + lk);
        accO[dd] = __builtin_amdgcn_mfma_f32_16x16x32_bf16(pf, vfr, accO[dd], 0, 0, 0);
      }
    }
    mb = mbn;
    __syncthreads();
    cur ^= 1;
  }
  const size_t hoff = (size_t)bh * kS * kHD;
  #pragma unroll
  for (int j = 0; j < 4; ++j){
    const float inv = 1.0f / __shfl(lsum, lk * 4 + j);
    const int row = qbase + lk * 4 + j;
    #pragma unroll
    for (int dd = 0; dd < 4; ++dd)
      O[hoff + (size_t)row * 64 + dd * 16 + lr] = f2b(accO[dd][j] * inv);
  }
}

// ------- fused split-K reduce + bias + residual add + LayerNorm -----------------
// a[i] = X[row,i] + (sum_z P[z][row,i] + bias[i]);  y = LN(a)*g+be
template <int NP, int PBF16, int OUT_B>
__global__ __launch_bounds__(256) void add_ln_kern(const float* __restrict__ X,
                                                   const void* __restrict__ P,
                                                   const float* __restrict__ bias,
                                                   const float* __restrict__ g,
                                                   const float* __restrict__ be,
                                                   float* __restrict__ Yf,
                                                   unsigned short* __restrict__ Yb){
  const int row = blockIdx.x;
  const int tid = threadIdx.x;
  const size_t pstride = (size_t)kTOK * kD;
  const int idx = row * 256 + tid;
  float r0 = 0.f, r1 = 0.f, r2 = 0.f, r3 = 0.f;
  #pragma unroll
  for (int z = 0; z < NP; ++z){
    if (PBF16){
      ushort4 u = ((const ushort4*)P)[z * (pstride / 4) + idx];
      r0 += b2f(u.x); r1 += b2f(u.y); r2 += b2f(u.z); r3 += b2f(u.w);
    } else {
      float4 p = ((const float4*)P)[z * (pstride / 4) + idx];
      r0 += p.x; r1 += p.y; r2 += p.z; r3 += p.w;
    }
  }
  const float4 bb = ((const float4*)bias)[tid];
  const float4 xv = ((const float4*)X)[idx];
  const float a0 = xv.x + r0 + bb.x, a1 = xv.y + r1 + bb.y;
  const float a2 = xv.z + r2 + bb.z, a3 = xv.w + r3 + bb.w;
  float s = a0 + a1 + a2 + a3;
  float q = a0*a0 + a1*a1 + a2*a2 + a3*a3;
  #pragma unroll
  for (int d = 1; d < 64; d <<= 1){ s += __shfl_xor(s, d); q += __shfl_xor(q, d); }
  __shared__ float red[8];
  const int wave = tid >> 6, lane = tid & 63;
  if (lane == 0){ red[wave] = s; red[4 + wave] = q; }
  __syncthreads();
  s = red[0] + red[1] + red[2] + red[3];
  q = red[4] + red[5] + red[6] + red[7];
  const float mu   = s * (1.0f / kD);
  const float var  = q * (1.0f / kD) - mu * mu;
  const float rstd = rsqrtf(var + 1e-5f);
  const float4 gv = ((const float4*)g)[tid];
  const float4 bv = ((const float4*)be)[tid];
  const float y0 = (a0 - mu) * rstd * gv.x + bv.x;
  const float y1 = (a1 - mu) * rstd * gv.y + bv.y;
  const float y2 = (a2 - mu) * rstd * gv.z + bv.z;
  const float y3 = (a3 - mu) * rstd * gv.w + bv.w;
  ((float4*)Yf)[idx] = make_float4(y0, y1, y2, y3);
  if (OUT_B)
    ((ushort4*)Yb)[idx] = make_ushort4(f2b(y0), f2b(y1), f2b(y2), f2b(y3));
}

} // namespace

extern "C" void kernel_launch(void* const* d_in, const int* in_sizes, int n_in,
                              void* d_out, int out_size, void* d_ws, size_t ws_size,
                              hipStream_t stream){
  (void)in_sizes; (void)n_in; (void)out_size;
  const float* x   = (const float*)d_in[0];
  const int*   mask= (const int*)d_in[1];
  const float* Wq  = (const float*)d_in[2];  const float* bq  = (const float*)d_in[3];
  const float* Wk  = (const float*)d_in[4];  const float* bk  = (const float*)d_in[5];
  const float* Wv  = (const float*)d_in[6];  const float* bv  = (const float*)d_in[7];
  const float* Wo  = (const float*)d_in[8];  const float* bo  = (const float*)d_in[9];
  const float* W1  = (const float*)d_in[10]; const float* b1  = (const float*)d_in[11];
  const float* W2  = (const float*)d_in[12]; const float* b2  = (const float*)d_in[13];
  const float* g1  = (const float*)d_in[14]; const float* be1 = (const float*)d_in[15];
  const float* g2  = (const float*)d_in[16]; const float* be2 = (const float*)d_in[17];

  char* ws = (char*)d_ws;
  const size_t MB = 1024 * 1024;
  if (ws_size < 96 * MB) return;   // need 96 MB of scratch

  // Layout (stage-by-stage lifetime-checked):
  unsigned short* W2T   = (unsigned short*)(ws + 0 * MB);    //  8 MB  preamble -> W2
  unsigned short* W1T   = (unsigned short*)(ws + 8 * MB);    //  8 MB  preamble -> W1
  unsigned short* WqkvT = (unsigned short*)(ws + 16 * MB);   //  6 MB  preamble -> QKV
  unsigned short* WoT   = (unsigned short*)(ws + 22 * MB);   //  2 MB  preamble -> Wo
  unsigned short* xb    = (unsigned short*)(ws + 24 * MB);   //  8 MB  preamble -> QKV
  unsigned short* qkv   = (unsigned short*)(ws + 32 * MB);   // 24 MB  QKV -> attn
  unsigned short* vt    = (unsigned short*)(ws + 56 * MB);   //  8 MB  vtrans -> attn
  unsigned short* av    = (unsigned short*)(ws + 64 * MB);   //  8 MB  attn -> Wo
  unsigned long long* mbits = (unsigned long long*)(ws + 72 * MB);     // 512 KB -> attn
  float* bqkv           = (float*)(ws + 72 * MB + 512 * 1024);         // 12 KB -> QKV
  // aliases after attn (qkv/vt/mbits dead in the stated order):
  float* woP            = (float*)(ws + 32 * MB);            // 32 MB [2][4096][1024] f32, Wo -> LN1
  float* y32            = (float*)(ws + 72 * MB);            // 16 MB LN1 -> LN2
  unsigned short* yb    = (unsigned short*)(ws + 88 * MB);   //  8 MB LN1 -> W1
  unsigned short* hb    = (unsigned short*)(ws + 40 * MB);   // 32 MB W1 -> W2 (over woP tail+vt+av, dead)
  unsigned short* w2p   = (unsigned short*)(ws + 8 * MB);    // 32 MB [4][4096][1024] bf16, W2 -> LN2

  dim3 blk(256);
  wtrans_kern<<<dim3(32, 32),  blk, 0, stream>>>(Wq, WqkvT,                   1024, 1024);
  wtrans_kern<<<dim3(32, 32),  blk, 0, stream>>>(Wk, WqkvT + 1024 * 1024,     1024, 1024);
  wtrans_kern<<<dim3(32, 32),  blk, 0, stream>>>(Wv, WqkvT + 2 * 1024 * 1024, 1024, 1024);
  wtrans_kern<<<dim3(32, 32),  blk, 0, stream>>>(Wo, WoT, 1024, 1024);
  wtrans_kern<<<dim3(128, 32), blk, 0, stream>>>(W1, W1T, 1024, 4096);
  wtrans_kern<<<dim3(32, 128), blk, 0, stream>>>(W2, W2T, 4096, 1024);
  cvt_bf16_kern<<<dim3(kTOK * kD / 1024), blk, 0, stream>>>(x, xb);
  maskbits_kern<<<dim3(kS * 32 / 4), blk, 0, stream>>>(mask, mbits);
  catbias_kern<<<dim3(12), blk, 0, stream>>>(bq, bk, bv, bqkv);

  // fused QKV projection: [4096][3072]
  gemm_bt_kern<1,0,1><<<dim3(24, 32), blk, 0, stream>>>(xb, WqkvT, bqkv, qkv, 4096, 3072, 1024);

  vtrans_kern<<<dim3(32, 32), blk, 0, stream>>>(qkv, vt);
  attn_kern<<<dim3(32, 32), blk, 0, stream>>>(qkv, vt, mbits, av);

  // Wo projection, split-K x2 -> f32 partials; LN1 fuses reduce + bo + residual(x)
  gemm_bt_kern<0,0,2><<<dim3(8, 32, 2), blk, 0, stream>>>(av, WoT, bo, woP, 4096, 1024, 1024);
  add_ln_kern<2,0,1><<<dim3(4096), blk, 0, stream>>>(x, woP, bo, g1, be1, y32, yb);

  // FFN
  gemm_bt_kern<1,1,1><<<dim3(32, 32), blk, 0, stream>>>(yb, W1T, b1, hb, 4096, 4096, 1024);
  // W2, split-K x4 -> bf16 partials; LN2 fuses reduce + b2 + residual(y32)
  gemm_bt_kern<1,0,4><<<dim3(8, 32, 4), blk, 0, stream>>>(hb, W2T, b2, w2p, 4096, 1024, 4096);
  add_ln_kern<4,1,0><<<dim3(4096), blk, 0, stream>>>(y32, w2p, b2, g2, be2, (float*)d_out, nullptr);
}

// Round 5
// 304.200 us; speedup vs baseline: 1.6429x; 1.0350x over previous
//
#include <hip/hip_runtime.h>
#include <cstdint>
#include <cstddef>

namespace {

constexpr int kS  = 2048;   // sequence
constexpr int kD  = 1024;   // model dim
constexpr int kHD = 64;     // head dim
constexpr int kTOK = 4096;  // B * S rows

typedef float f32x4 __attribute__((ext_vector_type(4)));
typedef __bf16 bf16x8 __attribute__((ext_vector_type(8)));
typedef unsigned short u16x8 __attribute__((ext_vector_type(8)));

__device__ __forceinline__ unsigned short f2b(float f){
  unsigned int u = __builtin_bit_cast(unsigned int, f);
  u += 0x7fffu + ((u >> 16) & 1u);      // RNE
  return (unsigned short)(u >> 16);
}

__device__ __forceinline__ float b2f(unsigned short u){
  return __builtin_bit_cast(float, (unsigned)u << 16);
}

__device__ __forceinline__ bf16x8 ldfrag(const unsigned short* p){
  return __builtin_bit_cast(bf16x8, *(const u16x8*)p);
}

__device__ __forceinline__ float fexp2(float x){
#if __has_builtin(__builtin_amdgcn_exp2f)
  return __builtin_amdgcn_exp2f(x);
#else
  return exp2f(x);
#endif
}

__device__ __forceinline__ void gl_lds16(const void* g, void* l){
  // async global->LDS, 16B per lane; LDS dest is wave-uniform base + lane*16
  __builtin_amdgcn_global_load_lds(
      (__attribute__((address_space(1))) void*)(void*)g,
      (__attribute__((address_space(3))) void*)l, 16, 0, 0);
}

// swizzled 16B fragment read from a 64-col bf16 tile: slot in [0,8)
__device__ __forceinline__ bf16x8 ld_swz(const unsigned short* tile, int row, int slot){
  return ldfrag(tile + row * 64 + (((slot ^ row) & 7) << 3));
}

// Stage one 64-seq-row K tile from the fused QKV buffer (head-block mapping):
// seq row s lives at Kg[(s>>4)*3072 + (s&15)*64 + d]. Source column pre-swizzled.
__device__ __forceinline__ void stageK(const unsigned short* Kg, unsigned short* lds,
                                       int wave, int lane, int t0){
  #pragma unroll
  for (int i = 0; i < 2; ++i){
    const int lin = i * 4096 + wave * 1024 + lane * 16;  // byte offset in tile
    const int r = lin >> 7;                               // tile row
    const int sl = (lin >> 4) & 7;                        // 16B slot
    const int sabs = t0 + r;
    gl_lds16(Kg + (size_t)(sabs >> 4) * 3072 + (sabs & 15) * 64 + (((sl ^ r) & 7) << 3),
             (char*)lds + i * 4096 + wave * 1024);
  }
}

// Stage a 64x64 slice of Vt [64][kS] (cols t0..t0+64), source-swizzled.
__device__ __forceinline__ void stageV(const unsigned short* Vh, unsigned short* lds,
                                       int wave, int lane, int t0){
  #pragma unroll
  for (int i = 0; i < 2; ++i){
    const int lin = i * 4096 + wave * 1024 + lane * 16;
    const int r = lin >> 7;
    const int sl = (lin >> 4) & 7;
    gl_lds16(Vh + (size_t)r * kS + t0 + (((sl ^ r) & 7) << 3),
             (char*)lds + i * 4096 + wave * 1024);
  }
}

// ---------------- f32 -> bf16 elementwise ----------------
__global__ __launch_bounds__(256) void cvt_bf16_kern(const float* __restrict__ X,
                                                     unsigned short* __restrict__ Y){
  int i = blockIdx.x * 256 + threadIdx.x;
  float4 v = ((const float4*)X)[i];
  ((ushort4*)Y)[i] = make_ushort4(f2b(v.x), f2b(v.y), f2b(v.z), f2b(v.w));
}

// ---------------- mask -> bit-packed u64, PERMUTED so lane bits are contiguous ----
__global__ __launch_bounds__(256) void maskbits_kern(const int* __restrict__ mask,
                                                     unsigned long long* __restrict__ mb){
  const int gw   = (blockIdx.x * 256 + threadIdx.x) >> 6;   // global wave id
  const int lane = threadIdx.x & 63;
  const int row  = gw >> 5, word = gw & 31;
  const int key  = ((lane >> 2) & 3) * 16 + ((lane >> 4) & 3) * 4 + (lane & 3);
  const int m = mask[(size_t)row * kS + word * 64 + key];
  const unsigned long long b = __ballot(m != 0);
  if (lane == 0) mb[(size_t)row * 32 + word] = b;
}

// ---------------- concat 3 bias vectors (1024 each) into one 3072 ----------------
__global__ __launch_bounds__(256) void catbias_kern(const float* __restrict__ a,
                                                    const float* __restrict__ b,
                                                    const float* __restrict__ c,
                                                    float* __restrict__ o){
  int i = blockIdx.x * 256 + threadIdx.x;
  float v = (i < 1024) ? a[i] : ((i < 2048) ? b[i - 1024] : c[i - 2048]);
  o[i] = v;
}

// ---------------- W[K,N] f32 -> Wt[N,K] bf16 (transpose+convert) ----------------
__global__ __launch_bounds__(256) void wtrans_kern(const float* __restrict__ W,
                                                   unsigned short* __restrict__ Wt,
                                                   int K, int N){
  __shared__ float t[32][33];
  int n0 = blockIdx.x * 32, k0 = blockIdx.y * 32;
  int tx = threadIdx.x & 31, ty = threadIdx.x >> 5;   // ty in [0,8)
  #pragma unroll
  for (int i = 0; i < 32; i += 8)
    t[ty + i][tx] = W[(size_t)(k0 + ty + i) * N + n0 + tx];
  __syncthreads();
  #pragma unroll
  for (int i = 0; i < 32; i += 8)
    Wt[(size_t)(n0 + ty + i) * K + k0 + tx] = f2b(t[tx][ty + i]);
}

// ---------------- V slice of fused QKV -> Vt [bh][64][kS] (bf16 transpose) -------
__global__ __launch_bounds__(256) void vtrans_kern(const unsigned short* __restrict__ QKV,
                                                   unsigned short* __restrict__ Vt){
  __shared__ unsigned short t[64][65];
  int bh = blockIdx.y, s0 = blockIdx.x * 64;
  const int rowbase = (bh >> 4) * 2048 + (bh & 15) * 128;
  const unsigned short* Vg = QKV + (size_t)rowbase * 3072 + 2048;
  unsigned short* Vth = Vt + (size_t)bh * kHD * kS;
  int tx = threadIdx.x & 63, ty = threadIdx.x >> 6;   // ty in [0,4)
  #pragma unroll
  for (int i = 0; i < 64; i += 4){
    const int s = s0 + ty + i;
    t[ty + i][tx] = Vg[(size_t)(s >> 4) * 3072 + (s & 15) * 64 + tx];
  }
  __syncthreads();
  #pragma unroll
  for (int i = 0; i < 64; i += 4)
    Vth[(size_t)(ty + i) * kS + s0 + tx] = t[tx][ty + i];
}

// ---------------- GEMM v2: 2-phase double-buffered, bank-swizzled ---------------
// C = A[M,K]*Bt[N,K]^T (+bias). XCD-aware bijective swizzle (nwg % 8 == 0).
// SPLITK>1: blockIdx.z owns K-chunk, writes partial (no bias) at C + z*M*N.
// LDS tile [128][32] bf16 (64B rows): slot swizzle p = s ^ ((row>>1)&3)
// (period-8 -> 8 distinct bank starts for 16 lanes -> conflict-free).
template <int OUT_BF16, int ACT_GELU, int SPLITK>
__global__ __launch_bounds__(256) void gemm_bt_kern(const unsigned short* __restrict__ A,
                                                    const unsigned short* __restrict__ Bt,
                                                    const float* __restrict__ bias,
                                                    void* __restrict__ C,
                                                    int M, int N, int K){
  __shared__ unsigned short As[2][128 * 32];
  __shared__ unsigned short Bs[2][128 * 32];
  int bid = blockIdx.y * gridDim.x + blockIdx.x;
  const int nwg = gridDim.x * gridDim.y;
  bid = (bid & 7) * (nwg >> 3) + (bid >> 3);            // T1 XCD swizzle
  const unsigned bx = (unsigned)bid % gridDim.x;
  const unsigned by = (unsigned)bid / gridDim.x;
  const int tid  = threadIdx.x;
  const int wave = tid >> 6, lane = tid & 63;
  const int wr = wave >> 1, wc = wave & 1;
  const int m0 = by << 7, n0 = bx << 7;
  const int lr = lane & 15, lk = lane >> 4;
  const int ch0 = wave * 2, ch1 = wave * 2 + 1;
  const int srow0 = ch0 * 16 + (lane >> 2), srow1 = ch1 * 16 + (lane >> 2);
  // inverse-swizzled source slot: physical slot (lane&3) of row srowX holds
  // logical slot (lane&3) ^ ((srowX>>1)&3); (srowX>>1)&3 == (lane>>3)&3.
  const int g   = (lane >> 3) & 3;
  const int sc0 = (((lane & 3) ^ g) << 3);
  const int kz   = K / SPLITK;
  const int kbeg = blockIdx.z * kz, kend = kbeg + kz;
  const unsigned short* Ap0 = A  + (size_t)(m0 + srow0) * K + sc0;
  const unsigned short* Ap1 = A  + (size_t)(m0 + srow1) * K + sc0;
  const unsigned short* Bp0 = Bt + (size_t)(n0 + srow0) * K + sc0;
  const unsigned short* Bp1 = Bt + (size_t)(n0 + srow1) * K + sc0;
  // read-side swizzled slot for fragment rows (row&7 == lr&7 in both quadrants)
  const int rslotA = ((lk ^ ((lr >> 1) & 3)) << 3);
  f32x4 acc[4][4] = {};
  // prologue: stage tile 0
  gl_lds16(Ap0 + kbeg, As[0] + ch0 * 512);
  gl_lds16(Ap1 + kbeg, As[0] + ch1 * 512);
  gl_lds16(Bp0 + kbeg, Bs[0] + ch0 * 512);
  gl_lds16(Bp1 + kbeg, Bs[0] + ch1 * 512);
  __syncthreads();                                      // drains vmcnt(0)
  int cur = 0;
  for (int k0 = kbeg; k0 < kend; k0 += 32){
    // 2-phase: issue next tile's staging BEFORE computing current tile
    if (k0 + 32 < kend){
      gl_lds16(Ap0 + k0 + 32, As[cur ^ 1] + ch0 * 512);
      gl_lds16(Ap1 + k0 + 32, As[cur ^ 1] + ch1 * 512);
      gl_lds16(Bp0 + k0 + 32, Bs[cur ^ 1] + ch0 * 512);
      gl_lds16(Bp1 + k0 + 32, Bs[cur ^ 1] + ch1 * 512);
    }
    bf16x8 af[4], bfr[4];
    #pragma unroll
    for (int m = 0; m < 4; ++m)
      af[m] = ldfrag(&As[cur][(wr * 64 + m * 16 + lr) * 32 + rslotA]);
    #pragma unroll
    for (int n = 0; n < 4; ++n)
      bfr[n] = ldfrag(&Bs[cur][(wc * 64 + n * 16 + lr) * 32 + rslotA]);
    #pragma unroll
    for (int m = 0; m < 4; ++m)
      #pragma unroll
      for (int n = 0; n < 4; ++n)
        acc[m][n] = __builtin_amdgcn_mfma_f32_16x16x32_bf16(af[m], bfr[n], acc[m][n], 0, 0, 0);
    __syncthreads();                                    // one drain+barrier per tile
    cur ^= 1;
  }
  unsigned short* Cb = (unsigned short*)C + (SPLITK > 1 ? (size_t)blockIdx.z * M * N : 0);
  float*          Cf = (float*)C          + (SPLITK > 1 ? (size_t)blockIdx.z * M * N : 0);
  #pragma unroll
  for (int n = 0; n < 4; ++n){
    const int col = n0 + wc * 64 + n * 16 + lr;
    const float bv = (SPLITK == 1) ? bias[col] : 0.0f;
    #pragma unroll
    for (int m = 0; m < 4; ++m){
      #pragma unroll
      for (int j = 0; j < 4; ++j){
        const int row = m0 + wr * 64 + m * 16 + lk * 4 + j;
        float v = acc[m][n][j] + bv;
        if (ACT_GELU) v = 0.5f * v * (1.0f + erff(v * 0.70710678118654752f));
        if (OUT_BF16) Cb[(size_t)row * N + col] = f2b(v);
        else          Cf[(size_t)row * N + col] = v;
      }
    }
  }
}

// ---------------- flash attention v3: no-max softmax (bounded scores), QBLK=64 ---
__global__ __launch_bounds__(256) void attn_kern(const unsigned short* __restrict__ QKV,
                                                 const unsigned short* __restrict__ Vt,
                                                 const unsigned long long* __restrict__ mbits,
                                                 unsigned short* __restrict__ O){
  __shared__ unsigned short Ks[2][64 * 64];
  __shared__ unsigned short Vs[2][64 * 64];     // [d][t], swizzled
  __shared__ unsigned short Ps[4][16 * 64];     // per-wave P [qrow][key], swizzled
  const int tid = threadIdx.x;
  const int wave = tid >> 6, lane = tid & 63;
  const int lr = lane & 15, lk = lane >> 4;
  const int bh = blockIdx.y;
  const int rowbase = (bh >> 4) * 2048 + (bh & 15) * 128;
  const unsigned short* Qg = QKV + (size_t)rowbase * 3072;
  const unsigned short* Kg = Qg + 1024;
  const unsigned short* Vh = Vt + (size_t)bh * kHD * kS;
  const int qbase = blockIdx.x * 64 + wave * 16;
  constexpr float kScl = 0.18033688011112042f;  // 0.125 * log2(e)

  bf16x8 qf[2];
  { const int qr = qbase + lr;
    const unsigned short* qp = Qg + (size_t)(qr >> 4) * 3072 + (qr & 15) * 64 + lk * 8;
    qf[0] = ldfrag(qp); qf[1] = ldfrag(qp + 32); }

  f32x4 accO[4] = {};
  float lsum = 0.f;
  unsigned short* Pw = Ps[wave];
  char* Pwb = (char*)Pw + lr * 128 + ((lk & 1) << 3);
  const int lr7 = lr & 7;

  const unsigned long long* mrp = mbits + (size_t)(qbase + lr) * 32;
  unsigned long long mb = mrp[0];

  stageK(Kg, Ks[0], wave, lane, 0);
  stageV(Vh, Vs[0], wave, lane, 0);
  __syncthreads();

  int cur = 0;
  for (int t = 0; t < kS / 64; ++t){
    unsigned long long mbn = 0;
    if (t < kS / 64 - 1){
      stageK(Kg, Ks[cur ^ 1], wave, lane, (t + 1) * 64);
      stageV(Vh, Vs[cur ^ 1], wave, lane, (t + 1) * 64);
      mbn = mrp[t + 1];
    }
    f32x4 sa[4] = {};
    #pragma unroll
    for (int kk = 0; kk < 2; ++kk)
      #pragma unroll
      for (int n = 0; n < 4; ++n){
        bf16x8 kf = ld_swz(Ks[cur], n * 16 + lr, kk * 4 + lk);
        sa[n] = __builtin_amdgcn_mfma_f32_16x16x32_bf16(kf, qf[kk], sa[n], 0, 0, 0);
      }
    const unsigned wb = (unsigned)(mb >> (lk * 16));
    float s = 0.f;
    #pragma unroll
    for (int n = 0; n < 4; ++n){
      float p0, p1, p2, p3;
      {
        float v0 = fexp2(sa[n][0] * kScl), v1 = fexp2(sa[n][1] * kScl);
        float v2 = fexp2(sa[n][2] * kScl), v3 = fexp2(sa[n][3] * kScl);
        const int s0 = ((int)(wb << (31 - (n * 4 + 0)))) >> 31;
        const int s1 = ((int)(wb << (31 - (n * 4 + 1)))) >> 31;
        const int s2 = ((int)(wb << (31 - (n * 4 + 2)))) >> 31;
        const int s3 = ((int)(wb << (31 - (n * 4 + 3)))) >> 31;
        p0 = __builtin_bit_cast(float, __builtin_bit_cast(int, v0) & s0);
        p1 = __builtin_bit_cast(float, __builtin_bit_cast(int, v1) & s1);
        p2 = __builtin_bit_cast(float, __builtin_bit_cast(int, v2) & s2);
        p3 = __builtin_bit_cast(float, __builtin_bit_cast(int, v3) & s3);
      }
      s += (p0 + p1) + (p2 + p3);
      unsigned r0, r1;
      asm("v_cvt_pk_bf16_f32 %0, %1, %2" : "=v"(r0) : "v"(p0), "v"(p1));
      asm("v_cvt_pk_bf16_f32 %0, %1, %2" : "=v"(r1) : "v"(p2), "v"(p3));
      *(uint2*)(Pwb + (((2 * n + (lk >> 1)) ^ lr7) << 4)) = make_uint2(r0, r1);
    }
    s += __shfl_xor(s, 16);
    s += __shfl_xor(s, 32);
    lsum += s;
    #pragma unroll
    for (int kk = 0; kk < 2; ++kk){
      bf16x8 pf = ld_swz(Pw, lr, kk * 4 + lk);
      #pragma unroll
      for (int dd = 0; dd < 4; ++dd){
        bf16x8 vfr = ld_swz(Vs[cur], dd * 16 + lr, kk * 4 + lk);
        accO[dd] = __builtin_amdgcn_mfma_f32_16x16x32_bf16(pf, vfr, accO[dd], 0, 0, 0);
      }
    }
    mb = mbn;
    __syncthreads();
    cur ^= 1;
  }
  const size_t hoff = (size_t)bh * kS * kHD;
  #pragma unroll
  for (int j = 0; j < 4; ++j){
    const float inv = 1.0f / __shfl(lsum, lk * 4 + j);
    const int row = qbase + lk * 4 + j;
    #pragma unroll
    for (int dd = 0; dd < 4; ++dd)
      O[hoff + (size_t)row * 64 + dd * 16 + lr] = f2b(accO[dd][j] * inv);
  }
}

// ------- fused split-K reduce + bias + residual add + LayerNorm -----------------
// a[i] = X[row,i] + (sum_z P[z][row,i] + bias[i]);  y = LN(a)*g+be
template <int NP, int PBF16, int OUT_B>
__global__ __launch_bounds__(256) void add_ln_kern(const float* __restrict__ X,
                                                   const void* __restrict__ P,
                                                   const float* __restrict__ bias,
                                                   const float* __restrict__ g,
                                                   const float* __restrict__ be,
                                                   float* __restrict__ Yf,
                                                   unsigned short* __restrict__ Yb){
  const int row = blockIdx.x;
  const int tid = threadIdx.x;
  const size_t pstride = (size_t)kTOK * kD;
  const int idx = row * 256 + tid;
  float r0 = 0.f, r1 = 0.f, r2 = 0.f, r3 = 0.f;
  #pragma unroll
  for (int z = 0; z < NP; ++z){
    if (PBF16){
      ushort4 u = ((const ushort4*)P)[z * (pstride / 4) + idx];
      r0 += b2f(u.x); r1 += b2f(u.y); r2 += b2f(u.z); r3 += b2f(u.w);
    } else {
      float4 p = ((const float4*)P)[z * (pstride / 4) + idx];
      r0 += p.x; r1 += p.y; r2 += p.z; r3 += p.w;
    }
  }
  const float4 bb = ((const float4*)bias)[tid];
  const float4 xv = ((const float4*)X)[idx];
  const float a0 = xv.x + r0 + bb.x, a1 = xv.y + r1 + bb.y;
  const float a2 = xv.z + r2 + bb.z, a3 = xv.w + r3 + bb.w;
  float s = a0 + a1 + a2 + a3;
  float q = a0*a0 + a1*a1 + a2*a2 + a3*a3;
  #pragma unroll
  for (int d = 1; d < 64; d <<= 1){ s += __shfl_xor(s, d); q += __shfl_xor(q, d); }
  __shared__ float red[8];
  const int wave = tid >> 6, lane = tid & 63;
  if (lane == 0){ red[wave] = s; red[4 + wave] = q; }
  __syncthreads();
  s = red[0] + red[1] + red[2] + red[3];
  q = red[4] + red[5] + red[6] + red[7];
  const float mu   = s * (1.0f / kD);
  const float var  = q * (1.0f / kD) - mu * mu;
  const float rstd = rsqrtf(var + 1e-5f);
  const float4 gv = ((const float4*)g)[tid];
  const float4 bv = ((const float4*)be)[tid];
  const float y0 = (a0 - mu) * rstd * gv.x + bv.x;
  const float y1 = (a1 - mu) * rstd * gv.y + bv.y;
  const float y2 = (a2 - mu) * rstd * gv.z + bv.z;
  const float y3 = (a3 - mu) * rstd * gv.w + bv.w;
  ((float4*)Yf)[idx] = make_float4(y0, y1, y2, y3);
  if (OUT_B)
    ((ushort4*)Yb)[idx] = make_ushort4(f2b(y0), f2b(y1), f2b(y2), f2b(y3));
}

} // namespace

extern "C" void kernel_launch(void* const* d_in, const int* in_sizes, int n_in,
                              void* d_out, int out_size, void* d_ws, size_t ws_size,
                              hipStream_t stream){
  (void)in_sizes; (void)n_in; (void)out_size;
  const float* x   = (const float*)d_in[0];
  const int*   mask= (const int*)d_in[1];
  const float* Wq  = (const float*)d_in[2];  const float* bq  = (const float*)d_in[3];
  const float* Wk  = (const float*)d_in[4];  const float* bk  = (const float*)d_in[5];
  const float* Wv  = (const float*)d_in[6];  const float* bv  = (const float*)d_in[7];
  const float* Wo  = (const float*)d_in[8];  const float* bo  = (const float*)d_in[9];
  const float* W1  = (const float*)d_in[10]; const float* b1  = (const float*)d_in[11];
  const float* W2  = (const float*)d_in[12]; const float* b2  = (const float*)d_in[13];
  const float* g1  = (const float*)d_in[14]; const float* be1 = (const float*)d_in[15];
  const float* g2  = (const float*)d_in[16]; const float* be2 = (const float*)d_in[17];

  char* ws = (char*)d_ws;
  const size_t MB = 1024 * 1024;
  if (ws_size < 96 * MB) return;   // need 96 MB of scratch

  // Layout (stage-by-stage lifetime-checked):
  unsigned short* W2T   = (unsigned short*)(ws + 0 * MB);    //  8 MB  preamble -> W2
  unsigned short* W1T   = (unsigned short*)(ws + 8 * MB);    //  8 MB  preamble -> W1
  unsigned short* WqkvT = (unsigned short*)(ws + 16 * MB);   //  6 MB  preamble -> QKV
  unsigned short* WoT   = (unsigned short*)(ws + 22 * MB);   //  2 MB  preamble -> Wo
  unsigned short* xb    = (unsigned short*)(ws + 24 * MB);   //  8 MB  preamble -> QKV
  unsigned short* qkv   = (unsigned short*)(ws + 32 * MB);   // 24 MB  QKV -> attn
  unsigned short* vt    = (unsigned short*)(ws + 56 * MB);   //  8 MB  vtrans -> attn
  unsigned short* av    = (unsigned short*)(ws + 64 * MB);   //  8 MB  attn -> Wo
  unsigned long long* mbits = (unsigned long long*)(ws + 72 * MB);     // 512 KB -> attn
  float* bqkv           = (float*)(ws + 72 * MB + 512 * 1024);         // 12 KB -> QKV
  // aliases after attn (qkv/vt/mbits dead in the stated order):
  float* woP            = (float*)(ws + 32 * MB);            // 32 MB [2][4096][1024] f32, Wo -> LN1
  float* y32            = (float*)(ws + 72 * MB);            // 16 MB LN1 -> LN2
  unsigned short* yb    = (unsigned short*)(ws + 88 * MB);   //  8 MB LN1 -> W1
  unsigned short* hb    = (unsigned short*)(ws + 40 * MB);   // 32 MB W1 -> W2 (over woP tail+vt+av, dead)
  unsigned short* w2p   = (unsigned short*)(ws + 8 * MB);    // 32 MB [4][4096][1024] bf16, W2 -> LN2

  dim3 blk(256);
  wtrans_kern<<<dim3(32, 32),  blk, 0, stream>>>(Wq, WqkvT,                   1024, 1024);
  wtrans_kern<<<dim3(32, 32),  blk, 0, stream>>>(Wk, WqkvT + 1024 * 1024,     1024, 1024);
  wtrans_kern<<<dim3(32, 32),  blk, 0, stream>>>(Wv, WqkvT + 2 * 1024 * 1024, 1024, 1024);
  wtrans_kern<<<dim3(32, 32),  blk, 0, stream>>>(Wo, WoT, 1024, 1024);
  wtrans_kern<<<dim3(128, 32), blk, 0, stream>>>(W1, W1T, 1024, 4096);
  wtrans_kern<<<dim3(32, 128), blk, 0, stream>>>(W2, W2T, 4096, 1024);
  cvt_bf16_kern<<<dim3(kTOK * kD / 1024), blk, 0, stream>>>(x, xb);
  maskbits_kern<<<dim3(kS * 32 / 4), blk, 0, stream>>>(mask, mbits);
  catbias_kern<<<dim3(12), blk, 0, stream>>>(bq, bk, bv, bqkv);

  // fused QKV projection: [4096][3072]
  gemm_bt_kern<1,0,1><<<dim3(24, 32), blk, 0, stream>>>(xb, WqkvT, bqkv, qkv, 4096, 3072, 1024);

  vtrans_kern<<<dim3(32, 32), blk, 0, stream>>>(qkv, vt);
  attn_kern<<<dim3(32, 32), blk, 0, stream>>>(qkv, vt, mbits, av);

  // Wo projection, split-K x2 -> f32 partials; LN1 fuses reduce + bo + residual(x)
  gemm_bt_kern<0,0,2><<<dim3(8, 32, 2), blk, 0, stream>>>(av, WoT, bo, woP, 4096, 1024, 1024);
  add_ln_kern<2,0,1><<<dim3(4096), blk, 0, stream>>>(x, woP, bo, g1, be1, y32, yb);

  // FFN
  gemm_bt_kern<1,1,1><<<dim3(32, 32), blk, 0, stream>>>(yb, W1T, b1, hb, 4096, 4096, 1024);
  // W2, split-K x4 -> bf16 partials; LN2 fuses reduce + b2 + residual(y32)
  gemm_bt_kern<1,0,4><<<dim3(8, 32, 4), blk, 0, stream>>>(hb, W2T, b2, w2p, 4096, 1024, 4096);
  add_ln_kern<4,1,0><<<dim3(4096), blk, 0, stream>>>(y32, w2p, b2, g2, be2, (float*)d_out, nullptr);
}